// Round 3
// baseline (429.927 us; speedup 1.0000x reference)
//
#include <hip/hip_runtime.h>
#include <cstddef>
#include <cstdint>

#define L_SEQ 4096
#define EMB   1024
#define NH    16
#define HD    64
#define N3    3072
#define CHUNK 64
#define NCHUNK 64
#define EPS 1e-6f

typedef __attribute__((ext_vector_type(8))) short   bf16x8;
typedef __attribute__((ext_vector_type(4))) short   bf16x4;
typedef __attribute__((ext_vector_type(4))) float   floatx4;

#define AS1 __attribute__((address_space(1)))
#define AS3 __attribute__((address_space(3)))

__device__ __forceinline__ void gload_lds16(const void* g, void* l) {
    __builtin_amdgcn_global_load_lds((AS1 const unsigned int*)g,
                                     (AS3 unsigned int*)l, 16, 0, 0);
}

// round-to-nearest-even fp32 -> bf16 bits
__device__ __forceinline__ short f2bf(float f) {
    union { float f; unsigned u; } a; a.f = f;
    unsigned r = a.u + 0x7fffu + ((a.u >> 16) & 1u);
    return (short)(r >> 16);
}
__device__ __forceinline__ float bf2f(short s) {
    union { unsigned u; float f; } a; a.u = ((unsigned)(unsigned short)s) << 16;
    return a.f;
}

// ---------------------------------------------------------------------------
// Grid barrier: two-level (16 groups x 64) sense-free generation barrier.
// bar[0..15]=group counters, bar[16]=root, bar[17]=generation.
// Writer-side release fence (buffer_wbl2) before arrival; reader-side acquire
// fence (buffer_inv) after release observed. Safe across XCDs.
// ---------------------------------------------------------------------------
__device__ __forceinline__ void gbar(unsigned* bar, int tid, int grp)
{
    __syncthreads();
    if (tid == 0) {
        __builtin_amdgcn_fence(__ATOMIC_RELEASE, "agent");
        unsigned* gen = bar + 17;
        const unsigned g0 =
            __hip_atomic_load(gen, __ATOMIC_RELAXED, __HIP_MEMORY_SCOPE_AGENT);
        bool released = false;
        if (__hip_atomic_fetch_add(bar + grp, 1u, __ATOMIC_RELAXED,
                                   __HIP_MEMORY_SCOPE_AGENT) == 63u) {
            __hip_atomic_store(bar + grp, 0u, __ATOMIC_RELAXED,
                               __HIP_MEMORY_SCOPE_AGENT);
            if (__hip_atomic_fetch_add(bar + 16, 1u, __ATOMIC_RELAXED,
                                       __HIP_MEMORY_SCOPE_AGENT) == 15u) {
                __hip_atomic_store(bar + 16, 0u, __ATOMIC_RELAXED,
                                   __HIP_MEMORY_SCOPE_AGENT);
                __hip_atomic_store(gen, g0 + 1u, __ATOMIC_RELEASE,
                                   __HIP_MEMORY_SCOPE_AGENT);
                released = true;
            }
        }
        if (!released)
            while (__hip_atomic_load(gen, __ATOMIC_RELAXED,
                                     __HIP_MEMORY_SCOPE_AGENT) == g0)
                __builtin_amdgcn_s_sleep(4);
        __builtin_amdgcn_fence(__ATOMIC_ACQUIRE, "agent");
    }
    __syncthreads();
}

// ---------------------------------------------------------------------------
// K0: fused prep — blocks [0,2048): x->bf16; [2048,2816): qkv_w^T;
// [2816,3072): out_w^T. Block 0 also zeroes the grid-barrier counters
// (the harness poison-fills the workspace between graph replays).
// ---------------------------------------------------------------------------
__device__ __forceinline__ void transpose_tile(const float* __restrict__ W,
                                               short* __restrict__ WT,
                                               int K, int N, int bx, int by,
                                               float (*t)[65], int tid)
{
    const int r  = tid >> 4;
    const int c4 = (tid & 15) << 2;
#pragma unroll
    for (int s = 0; s < 4; ++s) {
        const int k = r + s * 16;
        const floatx4 v = *(const floatx4*)&W[(size_t)(by * 64 + k) * N + bx * 64 + c4];
        t[k][c4 + 0] = v[0]; t[k][c4 + 1] = v[1];
        t[k][c4 + 2] = v[2]; t[k][c4 + 3] = v[3];
    }
    __syncthreads();
#pragma unroll
    for (int s = 0; s < 4; ++s) {
        const int n = r + s * 16;
        bf16x4 o;
        o[0] = f2bf(t[c4 + 0][n]); o[1] = f2bf(t[c4 + 1][n]);
        o[2] = f2bf(t[c4 + 2][n]); o[3] = f2bf(t[c4 + 3][n]);
        *(bf16x4*)&WT[(size_t)(bx * 64 + n) * K + by * 64 + c4] = o;
    }
}

__global__ __launch_bounds__(256)
void prep(const float* __restrict__ x, short* __restrict__ xb,
          const float* __restrict__ qkv_w, short* __restrict__ qwt,
          const float* __restrict__ out_w, short* __restrict__ owt,
          unsigned* __restrict__ bar)
{
    __shared__ float t[64][65];
    const int b = blockIdx.x;
    const int tid = threadIdx.x;
    if (b == 0 && tid < 32) bar[tid] = 0u;     // re-arm grid barrier each replay
    if (b < 2048) {
        const int i = b * 256 + tid;
        const floatx4 a = *(const floatx4*)(x + (size_t)i * 8);
        const floatx4 c = *(const floatx4*)(x + (size_t)i * 8 + 4);
        bf16x8 o;
        o[0] = f2bf(a[0]); o[1] = f2bf(a[1]); o[2] = f2bf(a[2]); o[3] = f2bf(a[3]);
        o[4] = f2bf(c[0]); o[5] = f2bf(c[1]); o[6] = f2bf(c[2]); o[7] = f2bf(c[3]);
        *(bf16x8*)(xb + (size_t)i * 8) = o;
    } else if (b < 2048 + 768) {
        const int u = b - 2048;
        transpose_tile(qkv_w, qwt, EMB, N3, u % 48, u / 48, t, tid);
    } else {
        const int u = b - 2816;
        transpose_tile(out_w, owt, EMB, EMB, u & 15, u >> 4, t, tid);
    }
}

// ---------------------------------------------------------------------------
// K1: qkv GEMM — 256x256 tile, BK=64, 8 waves (2Mx4N), 8-phase schedule.
// (unchanged from R2 — verified correct)
// ---------------------------------------------------------------------------
#define MFMA16 __builtin_amdgcn_mfma_f32_16x16x32_bf16

__global__ __launch_bounds__(512, 2)
void mfma_gemm_qkv256(const short* __restrict__ A, const short* __restrict__ BT,
                      const float* __restrict__ bias,
                      short* __restrict__ OQ, short* __restrict__ OK,
                      short* __restrict__ OV)
{
    __shared__ __align__(16) short lds[65536];   // 128 KiB
    const int tid  = threadIdx.x;
    const int lane = tid & 63;
    const int wave = tid >> 6;           // 0..7
    const int wr   = wave >> 2;          // 0..1 (M half)
    const int wc   = wave & 3;           // 0..3 (N quarter)
    const int frow = lane & 15;
    const int quad = lane >> 4;
    const int q8   = quad * 8;
    const int bx = blockIdx.x;           // N tiles: 12
    const int by = blockIdx.y;           // M tiles: 16

    const short* Ab = A  + (size_t)(by * 256) * 1024;
    const short* Bb = BT + (size_t)(bx * 256) * 1024;

    const int trow = tid >> 3;
    const int ccol = (tid & 7) * 8;
    const int scol = ccol ^ ((trow & 12) << 2);
    const int sx = (frow & 12) << 2;
    const int wcb = wc * 64 + frow;

#define STG(LBASE, GPTR) do {                                               \
        const short* g_ = (GPTR);                                           \
        _Pragma("unroll")                                                   \
        for (int j_ = 0; j_ < 2; ++j_) {                                    \
            const int r_ = j_ * 64 + trow;                                  \
            gload_lds16(g_ + (size_t)r_ * 1024 + scol,                      \
                        &lds[(LBASE) + r_ * 64 + ccol]);                    \
        }                                                                   \
    } while (0)

#define LDA(BASE, R, KS) \
    (*(const bf16x8*)&lds[(BASE) + (R) * 64 + ((((KS) * 32) + q8) ^ sx)])

    floatx4 acc[8][4] = {};
    bf16x8  bq[4][2];

#define PHASE(ABASE, BBASE, QD, RDB, VM, ...) do {                          \
        const int Rr_ = wr * 128 + (QD) * 32 + frow;                        \
        bf16x8 a0_ = LDA((ABASE), Rr_,      0);                             \
        bf16x8 a1_ = LDA((ABASE), Rr_,      1);                             \
        bf16x8 a2_ = LDA((ABASE), Rr_ + 16, 0);                             \
        bf16x8 a3_ = LDA((ABASE), Rr_ + 16, 1);                             \
        if (RDB) {                                                          \
            _Pragma("unroll")                                               \
            for (int ni_ = 0; ni_ < 4; ++ni_) {                             \
                bq[ni_][0] = LDA((BBASE), wcb + ni_ * 16, 0);               \
                bq[ni_][1] = LDA((BBASE), wcb + ni_ * 16, 1);               \
            }                                                               \
        }                                                                   \
        __VA_ARGS__;                                                        \
        __builtin_amdgcn_sched_barrier(0);                                  \
        __builtin_amdgcn_s_barrier();                                       \
        asm volatile("s_waitcnt lgkmcnt(0)" ::: "memory");                  \
        __builtin_amdgcn_sched_barrier(0);                                  \
        __builtin_amdgcn_s_setprio(1);                                      \
        _Pragma("unroll")                                                   \
        for (int ni_ = 0; ni_ < 4; ++ni_) {                                 \
            acc[2*(QD)  ][ni_] = MFMA16(a0_, bq[ni_][0], acc[2*(QD)  ][ni_], 0,0,0); \
            acc[2*(QD)  ][ni_] = MFMA16(a1_, bq[ni_][1], acc[2*(QD)  ][ni_], 0,0,0); \
            acc[2*(QD)+1][ni_] = MFMA16(a2_, bq[ni_][0], acc[2*(QD)+1][ni_], 0,0,0); \
            acc[2*(QD)+1][ni_] = MFMA16(a3_, bq[ni_][1], acc[2*(QD)+1][ni_], 0,0,0); \
        }                                                                   \
        __builtin_amdgcn_s_setprio(0);                                      \
        if (VM) asm volatile("s_waitcnt vmcnt(4)" ::: "memory");            \
        __builtin_amdgcn_s_barrier();                                       \
        __builtin_amdgcn_sched_barrier(0);                                  \
    } while (0)

    STG(0,     Ab);
    STG(8192,  Ab + 131072);
    STG(16384, Bb);
    STG(24576, Bb + 131072);
    STG(49152, Bb + 64);
    STG(57344, Bb + 131072 + 64);
    asm volatile("s_waitcnt vmcnt(4)" ::: "memory");
    __builtin_amdgcn_s_barrier();
    __builtin_amdgcn_sched_barrier(0);

#pragma unroll 1
    for (int it = 0; it < 8; ++it) {
        const int k1  = (2 * it + 1) * 64;
        const int kn0 = ((2 * it + 2) & 15) * 64;
        const int kn1 = ((2 * it + 3) & 15) * 64;

        PHASE(0, 16384, 0, 1, 0,
              STG(32768, Ab + k1); STG(40960, Ab + 131072 + k1));
        PHASE(0, 16384, 1, 0, 0, STG(16384, Bb + kn0));
        PHASE(0, 16384, 2, 0, 0, STG(24576, Bb + 131072 + kn0));
        PHASE(0, 16384, 3, 0, 1, ((void)0));
        PHASE(32768, 49152, 0, 1, 0, STG(0,    Ab + kn0));
        PHASE(32768, 49152, 1, 0, 0, STG(8192, Ab + 131072 + kn0));
        PHASE(32768, 49152, 2, 0, 0, STG(49152, Bb + kn1));
        PHASE(32768, 49152, 3, 0, 1, STG(57344, Bb + 131072 + kn1));
    }

    __syncthreads();

    const int wbase = wave * 8192;
    const int colg0 = bx * 256 + wc * 64;
    const int rsel  = colg0 >> 10;
    const bool do_elu = rsel < 2;
    short* obase = (rsel == 0) ? OQ : (rsel == 1 ? OK : OV);
    const int h  = (colg0 >> 6) & 15;
    const int L0 = by * 256 + wr * 128;
#pragma unroll
    for (int ni = 0; ni < 4; ++ni) {
        const float bv = bias[colg0 + ni * 16 + frow];
#pragma unroll
        for (int mi = 0; mi < 8; ++mi)
#pragma unroll
            for (int r = 0; r < 4; ++r) {
                float v = acc[mi][ni][r] + bv;
                if (do_elu) v = (v > 0.f) ? (v + 1.f) : __expf(v);
                lds[wbase + (mi * 16 + quad * 4 + r) * 64 + ni * 16 + frow] = f2bf(v);
            }
    }
#pragma unroll
    for (int s = 0; s < 16; ++s) {
        const int chunk = s * 64 + lane;
        const int row = chunk >> 3, c8 = (chunk & 7) * 8;
        *(bf16x8*)&obase[((size_t)(h * L_SEQ + L0 + row)) * HD + c8] =
            *(const bf16x8*)&lds[wbase + row * 64 + c8];
    }
#undef PHASE
#undef LDA
#undef STG
}

// ---------------------------------------------------------------------------
// K2: fused tail — 4 phases separated by grid barriers, 1024 blocks x 256.
//   phase1: per-(h,c) chunk state sums (old chunk_state)
//   phase2: exclusive prefix over chunks (old prefix_scan, blocks 0..255)
//   phase3: per-(h,c) intra-chunk attention (old chunk_attn)
//   phase4: out-projection GEMM 64x128 (old mfma_gemm_out, blocks 0..511)
// Residency: LDS 24.6KB (6/CU), VGPR<=128 via launch_bounds (4/CU), waves 8/CU
// -> binding 4 blocks/CU x 256 CU = 1024 = grid, all co-resident. [guarantee]
// ---------------------------------------------------------------------------
#define SP 72

__global__ __launch_bounds__(256, 4)
void tail(const short* __restrict__ Qb, const short* __restrict__ Kb,
          const short* __restrict__ Vb,
          short* __restrict__ ScTb, float* __restrict__ zc,
          short* __restrict__ S0b, short* __restrict__ attnb,
          const short* __restrict__ owt, const float* __restrict__ out_b,
          float* __restrict__ out, unsigned* __restrict__ bar)
{
    __shared__ __align__(16) short shm[12288];   // max(9216, 9288, 12288) shorts
    const int tid  = threadIdx.x;
    const int lane = tid & 63;
    const int wave = tid >> 6;
    const int bidf = blockIdx.y * 64 + blockIdx.x;   // 0..1023
    const int frow = lane & 15;
    const int quad = lane >> 4;
    const int fko  = quad << 3;

    // ---------------- phase 1: chunk_state ----------------
    {
        short* Vt = shm;                 // 64 x SP
        short* Kt = shm + 64 * SP;       // 64 x SP
        const int c = blockIdx.x, h = blockIdx.y;
        const int wm = wave << 4;
        const short* Kg = Kb + ((size_t)h * L_SEQ + (size_t)c * CHUNK) * HD;
        const short* Vg = Vb + ((size_t)h * L_SEQ + (size_t)c * CHUNK) * HD;

#pragma unroll
        for (int q = 0; q < 2; ++q) {
            const int idx = q * 256 + tid;
            const int l = idx >> 3, c8 = (idx & 7) << 3;
            const bf16x8 vv = *(const bf16x8*)&Vg[l * 64 + c8];
            const bf16x8 kk = *(const bf16x8*)&Kg[l * 64 + c8];
#pragma unroll
            for (int j = 0; j < 8; ++j) {
                Vt[(c8 + j) * SP + l] = vv[j];
                Kt[(c8 + j) * SP + l] = kk[j];
            }
        }
        __syncthreads();

        const bf16x8 af0 = *(const bf16x8*)&Vt[(wm + frow) * SP + fko];
        const bf16x8 af1 = *(const bf16x8*)&Vt[(wm + frow) * SP + 32 + fko];

        floatx4 acc[4] = {};
#pragma unroll
        for (int n = 0; n < 4; ++n) {
            const bf16x8 kf0 = *(const bf16x8*)&Kt[(n * 16 + frow) * SP + fko];
            const bf16x8 kf1 = *(const bf16x8*)&Kt[(n * 16 + frow) * SP + 32 + fko];
            acc[n] = MFMA16(af0, kf0, acc[n], 0, 0, 0);
            acc[n] = MFMA16(af1, kf1, acc[n], 0, 0, 0);
        }

        short* Sout = ScTb + (size_t)(h * NCHUNK + c) * 4096;
#pragma unroll
        for (int n = 0; n < 4; ++n)
#pragma unroll
            for (int r = 0; r < 4; ++r) {
                const int e = wm + quad * 4 + r;
                const int d = n * 16 + frow;
                Sout[e * 64 + d] = f2bf(acc[n][r]);
            }

        if (wave == 0) {
            bf16x8 ones;
#pragma unroll
            for (int j = 0; j < 8; ++j) ones[j] = (short)0x3F80;
            floatx4 zacc[4] = {};
#pragma unroll
            for (int n = 0; n < 4; ++n) {
                const bf16x8 kf0 = *(const bf16x8*)&Kt[(n * 16 + frow) * SP + fko];
                const bf16x8 kf1 = *(const bf16x8*)&Kt[(n * 16 + frow) * SP + 32 + fko];
                zacc[n] = MFMA16(ones, kf0, zacc[n], 0, 0, 0);
                zacc[n] = MFMA16(ones, kf1, zacc[n], 0, 0, 0);
            }
            if (quad == 0) {
#pragma unroll
                for (int n = 0; n < 4; ++n)
                    zc[(size_t)(h * NCHUNK + c) * 64 + n * 16 + frow] = zacc[n][0];
            }
        }
    }
    gbar(bar, tid, blockIdx.y);

    // ---------------- phase 2: prefix scan (blocks 0..255) ----------------
    if (bidf < 256) {
        const int g = bidf * 256 + tid;
        const int h  = g >> 12;
        const int ed = g & 4095;
        const int e  = ed >> 6;
        const int d  = ed & 63;
        const short* src = ScTb + (size_t)h * NCHUNK * 4096 + ed;
        float run = 0.f;
        for (int cb = 0; cb < NCHUNK; cb += 8) {
            short v[8];
#pragma unroll
            for (int u = 0; u < 8; ++u) v[u] = src[(size_t)(cb + u) * 4096];
#pragma unroll
            for (int u = 0; u < 8; ++u) {
                S0b[((size_t)((h * NCHUNK + cb + u) * 65 + e)) * 64 + d] = f2bf(run);
                run += bf2f(v[u]);
            }
        }
        if (g < NH * HD) {
            const int h2 = g >> 6, d2 = g & 63;
            float rz = 0.f;
            for (int cb = 0; cb < NCHUNK; cb += 8) {
                float w[8];
#pragma unroll
                for (int u = 0; u < 8; ++u)
                    w[u] = zc[((size_t)(h2 * NCHUNK + cb + u)) * HD + d2];
#pragma unroll
                for (int u = 0; u < 8; ++u) {
                    S0b[((size_t)((h2 * NCHUNK + cb + u) * 65 + 64)) * 64 + d2] = f2bf(rz);
                    rz += w[u];
                }
            }
        }
    }
    gbar(bar, tid, blockIdx.y);

    // ---------------- phase 3: chunk_attn ----------------
    {
        short* Vs = shm;                 // 65 x SP (row 64 = ones)
        short* As = shm + 65 * SP;       // 64 x SP
        const int c = blockIdx.x, h = blockIdx.y;
        const int wm = wave << 4;
        const size_t rb = ((size_t)h * L_SEQ + (size_t)c * CHUNK) * HD;
        const short* Qg = Qb + rb;
        const short* Kg = Kb + rb;
        const short* Vg = Vb + rb;
        const short* Sg = S0b + (size_t)(h * NCHUNK + c) * 65 * 64;

#pragma unroll
        for (int q = 0; q < 2; ++q) {
            const int idx = q * 256 + tid;
            const int row = idx >> 3, c8 = (idx & 7) << 3;
            const bf16x8 vv = *(const bf16x8*)&Vg[row * 64 + c8];
#pragma unroll
            for (int j = 0; j < 8; ++j) Vs[(c8 + j) * SP + row] = vv[j];
        }
        if (tid < 64) Vs[64 * SP + tid] = (short)0x3F80;
        __syncthreads();

        const bf16x8 qf0 = *(const bf16x8*)&Qg[(wm + frow) * 64 + fko];
        const bf16x8 qf1 = *(const bf16x8*)&Qg[(wm + frow) * 64 + 32 + fko];

        floatx4 sacc[4] = {};
#pragma unroll
        for (int n = 0; n < 4; ++n) {
            const bf16x8 kf0 = *(const bf16x8*)&Kg[(n * 16 + frow) * 64 + fko];
            const bf16x8 kf1 = *(const bf16x8*)&Kg[(n * 16 + frow) * 64 + 32 + fko];
            sacc[n] = MFMA16(qf0, kf0, sacc[n], 0, 0, 0);
            sacc[n] = MFMA16(qf1, kf1, sacc[n], 0, 0, 0);
        }
#pragma unroll
        for (int n = 0; n < 4; ++n)
#pragma unroll
            for (int r = 0; r < 4; ++r) {
                const int i = wm + quad * 4 + r;
                const int j = n * 16 + frow;
                As[i * SP + j] = (j <= i) ? f2bf(sacc[n][r]) : (short)0;
            }
        const bf16x8 af0 = *(const bf16x8*)&As[(wm + frow) * SP + fko];
        const bf16x8 af1 = *(const bf16x8*)&As[(wm + frow) * SP + 32 + fko];

        floatx4 oacc[5] = {};
#pragma unroll
        for (int n = 0; n < 4; ++n) {
            const bf16x8 vf0 = *(const bf16x8*)&Vs[(n * 16 + frow) * SP + fko];
            const bf16x8 vf1 = *(const bf16x8*)&Vs[(n * 16 + frow) * SP + 32 + fko];
            oacc[n] = MFMA16(af0, vf0, oacc[n], 0, 0, 0);
            oacc[n] = MFMA16(af1, vf1, oacc[n], 0, 0, 0);
            const bf16x8 sf0 = *(const bf16x8*)&Sg[(n * 16 + frow) * 64 + fko];
            const bf16x8 sf1 = *(const bf16x8*)&Sg[(n * 16 + frow) * 64 + 32 + fko];
            oacc[n] = MFMA16(qf0, sf0, oacc[n], 0, 0, 0);
            oacc[n] = MFMA16(qf1, sf1, oacc[n], 0, 0, 0);
        }
        {
            const bf16x8 vf0 = *(const bf16x8*)&Vs[64 * SP + fko];
            const bf16x8 vf1 = *(const bf16x8*)&Vs[64 * SP + 32 + fko];
            oacc[4] = MFMA16(af0, vf0, oacc[4], 0, 0, 0);
            oacc[4] = MFMA16(af1, vf1, oacc[4], 0, 0, 0);
            const bf16x8 sf0 = *(const bf16x8*)&Sg[64 * 64 + fko];
            const bf16x8 sf1 = *(const bf16x8*)&Sg[64 * 64 + 32 + fko];
            oacc[4] = MFMA16(qf0, sf0, oacc[4], 0, 0, 0);
            oacc[4] = MFMA16(qf1, sf1, oacc[4], 0, 0, 0);
        }
#pragma unroll
        for (int r = 0; r < 4; ++r) {
            const float norm = __shfl(oacc[4][r], lane & 48) + EPS;
            const float inv = 1.f / norm;
            const int i = wm + quad * 4 + r;
#pragma unroll
            for (int n = 0; n < 4; ++n)
                As[i * SP + n * 16 + frow] = f2bf(oacc[n][r] * inv);
        }
        __syncthreads();
#pragma unroll
        for (int t = 0; t < 2; ++t) {
            const int idx = t * 256 + tid;
            const int row = idx >> 3, c8 = (idx & 7) << 3;
            *(bf16x8*)&attnb[(size_t)(c * CHUNK + row) * EMB + h * HD + c8] =
                *(const bf16x8*)&As[row * SP + c8];
        }
    }
    gbar(bar, tid, blockIdx.y);

    // ---------------- phase 4: out GEMM (blocks 0..511) ----------------
    if (bidf < 512) {
        short* smem = shm;
        short* pan[4] = { smem, smem + 2048, smem + 6144, smem + 8192 };
        const int wm = (wave >> 1) * 32;
        const int wn = (wave & 1) * 64;
        const int bx = bidf & 7;
        const int by = bidf >> 3;

        const short* Ab = attnb + (size_t)(by * 64) * 1024;
        const short* Bb = owt   + (size_t)(bx * 128) * 1024;

        floatx4 acc[2][4] = {};

        for (int k0 = 0; k0 < 1024; k0 += 64) {
#pragma unroll
            for (int p = 0; p < 2; ++p) {
                const int kp = k0 + p * 32;
                {
                    const int row = tid >> 2;
                    const int kc  = (tid & 3) << 3;
                    gload_lds16(Ab + (size_t)row * 1024 + kp + kc, &pan[p * 2 + 0][tid << 3]);
                }
#pragma unroll
                for (int q = 0; q < 2; ++q) {
                    const int ib = q * 256 + tid;
                    const int row = ib >> 2;
                    const int kc  = (ib & 3) << 3;
                    gload_lds16(Bb + (size_t)row * 1024 + kp + kc, &pan[p * 2 + 1][ib << 3]);
                }
            }
            __syncthreads();
#pragma unroll
            for (int p = 0; p < 2; ++p) {
                bf16x8 af[2], bfv[4];
#pragma unroll
                for (int mi = 0; mi < 2; ++mi)
                    af[mi] = *(const bf16x8*)&pan[p * 2 + 0][(wm + mi * 16 + frow) * 32 + fko];
#pragma unroll
                for (int ni = 0; ni < 4; ++ni)
                    bfv[ni] = *(const bf16x8*)&pan[p * 2 + 1][(wn + ni * 16 + frow) * 32 + fko];
#pragma unroll
                for (int mi = 0; mi < 2; ++mi)
#pragma unroll
                    for (int ni = 0; ni < 4; ++ni)
                        acc[mi][ni] = MFMA16(af[mi], bfv[ni], acc[mi][ni], 0, 0, 0);
            }
            __syncthreads();
        }

        const int rq = quad << 2;
#pragma unroll
        for (int ni = 0; ni < 4; ++ni) {
            const int n = bx * 128 + wn + ni * 16 + frow;
            const float bv = out_b[n];
#pragma unroll
            for (int mi = 0; mi < 2; ++mi)
#pragma unroll
                for (int r = 0; r < 4; ++r) {
                    const int m = by * 64 + wm + mi * 16 + rq + r;
                    out[(size_t)m * 1024 + n] = acc[mi][ni][r] + bv;
                }
        }
    }
}

// ---------------------------------------------------------------------------
extern "C" void kernel_launch(void* const* d_in, const int* in_sizes, int n_in,
                              void* d_out, int out_size, void* d_ws, size_t ws_size,
                              hipStream_t stream)
{
    const float* x     = (const float*)d_in[0];
    const float* qkv_w = (const float*)d_in[1];
    const float* qkv_b = (const float*)d_in[2];
    const float* out_w = (const float*)d_in[3];
    const float* out_b = (const float*)d_in[4];
    float* out = (float*)d_out;

    short* ws    = (short*)d_ws;
    short* Qb    = ws;                   // head-major bf16, 4194304 each
    short* Kb    = Qb + 4194304;
    short* Vb    = Kb + 4194304;
    short* xb    = Vb + 4194304;
    short* qwt   = xb + 4194304;         // 3072 x 1024
    short* owt   = qwt + 3145728;        // 1024 x 1024
    short* attnb = owt + 1048576;        // 4096 x 1024
    short* ScTb  = attnb + 4194304;      // 1024 * 64 * 64
    short* S0b   = ScTb + 4194304;       // 1024 * 65 * 64
    float* zc    = (float*)(S0b + 4259840);    // 65536 fp32
    unsigned* bar = (unsigned*)(zc + 65536);   // 18 counters (32 reserved)

    prep<<<dim3(3072), 256, 0, stream>>>(x, xb, qkv_w, qwt, out_w, owt, bar);
    mfma_gemm_qkv256<<<dim3(N3 / 256, L_SEQ / 256), 512, 0, stream>>>(
        xb, qwt, qkv_b, Qb, Kb, Vb);
    tail<<<dim3(NCHUNK, NH), 256, 0, stream>>>(
        Qb, Kb, Vb, ScTb, zc, S0b, attnb, owt, out_b, out, bar);
}

// Round 4
// 211.704 us; speedup vs baseline: 2.0308x; 2.0308x over previous
//
#include <hip/hip_runtime.h>
#include <cstddef>
#include <cstdint>

#define L_SEQ 4096
#define EMB   1024
#define NH    16
#define HD    64
#define N3    3072
#define CHUNK 64
#define NCHUNK 64
#define EPS 1e-6f

typedef __attribute__((ext_vector_type(8))) short   bf16x8;
typedef __attribute__((ext_vector_type(4))) short   bf16x4;
typedef __attribute__((ext_vector_type(4))) float   floatx4;

#define AS1 __attribute__((address_space(1)))
#define AS3 __attribute__((address_space(3)))

__device__ __forceinline__ void gload_lds16(const void* g, void* l) {
    __builtin_amdgcn_global_load_lds((AS1 const unsigned int*)g,
                                     (AS3 unsigned int*)l, 16, 0, 0);
}

// round-to-nearest-even fp32 -> bf16 bits
__device__ __forceinline__ short f2bf(float f) {
    union { float f; unsigned u; } a; a.f = f;
    unsigned r = a.u + 0x7fffu + ((a.u >> 16) & 1u);
    return (short)(r >> 16);
}
__device__ __forceinline__ float bf2f(short s) {
    union { unsigned u; float f; } a; a.u = ((unsigned)(unsigned short)s) << 16;
    return a.f;
}

// device-coherent (sc1) helpers: relaxed agent atomics bypass L2 -> IF
__device__ __forceinline__ void cstore_u32(void* p, unsigned v) {
    __hip_atomic_store((unsigned*)p, v, __ATOMIC_RELAXED,
                       __HIP_MEMORY_SCOPE_AGENT);
}
__device__ __forceinline__ void cstore_u64(void* p, unsigned long long v) {
    __hip_atomic_store((unsigned long long*)p, v, __ATOMIC_RELAXED,
                       __HIP_MEMORY_SCOPE_AGENT);
}
__device__ __forceinline__ void cstore_f32(float* p, float v) {
    __hip_atomic_store(p, v, __ATOMIC_RELAXED, __HIP_MEMORY_SCOPE_AGENT);
}

// ---------------------------------------------------------------------------
// Grid barrier, fence-free. Data visibility comes from sc1 (agent-scope)
// stores of all phase-crossing buffers + vmcnt(0) before arrival — NO L2
// writeback/invalidate needed (that was R3's 93us/barrier pathology).
// 3-level arrival tree: 64 groups x16 -> 8 supergroups x8 -> root x8 -> flag.
// One instance per barrier use (no generation logic); prep re-zeroes.
// ---------------------------------------------------------------------------
__device__ __forceinline__ void gbar(unsigned* bar, int tid, int bidf, int inst)
{
    __syncthreads();
    if (tid == 0) {
        asm volatile("s_waitcnt vmcnt(0) lgkmcnt(0)" ::: "memory");
        unsigned* b = bar + inst * 128;
        if (__hip_atomic_fetch_add(b + (bidf >> 4), 1u, __ATOMIC_RELAXED,
                                   __HIP_MEMORY_SCOPE_AGENT) == 15u)
            if (__hip_atomic_fetch_add(b + 64 + (bidf >> 7), 1u, __ATOMIC_RELAXED,
                                       __HIP_MEMORY_SCOPE_AGENT) == 7u)
                if (__hip_atomic_fetch_add(b + 72, 1u, __ATOMIC_RELAXED,
                                           __HIP_MEMORY_SCOPE_AGENT) == 7u)
                    __hip_atomic_store(b + 73, 1u, __ATOMIC_RELAXED,
                                       __HIP_MEMORY_SCOPE_AGENT);
        while (!__hip_atomic_load(b + 73, __ATOMIC_RELAXED,
                                  __HIP_MEMORY_SCOPE_AGENT))
            __builtin_amdgcn_s_sleep(16);
        asm volatile("" ::: "memory");
    }
    __syncthreads();
}

// ---------------------------------------------------------------------------
// K0: fused prep — blocks [0,2048): x->bf16; [2048,2816): qkv_w^T;
// [2816,3072): out_w^T. Block 0 re-zeroes the 3 barrier instances (384 u32)
// every replay (harness poison-fills the workspace between replays).
// ---------------------------------------------------------------------------
__device__ __forceinline__ void transpose_tile(const float* __restrict__ W,
                                               short* __restrict__ WT,
                                               int K, int N, int bx, int by,
                                               float (*t)[65], int tid)
{
    const int r  = tid >> 4;
    const int c4 = (tid & 15) << 2;
#pragma unroll
    for (int s = 0; s < 4; ++s) {
        const int k = r + s * 16;
        const floatx4 v = *(const floatx4*)&W[(size_t)(by * 64 + k) * N + bx * 64 + c4];
        t[k][c4 + 0] = v[0]; t[k][c4 + 1] = v[1];
        t[k][c4 + 2] = v[2]; t[k][c4 + 3] = v[3];
    }
    __syncthreads();
#pragma unroll
    for (int s = 0; s < 4; ++s) {
        const int n = r + s * 16;
        bf16x4 o;
        o[0] = f2bf(t[c4 + 0][n]); o[1] = f2bf(t[c4 + 1][n]);
        o[2] = f2bf(t[c4 + 2][n]); o[3] = f2bf(t[c4 + 3][n]);
        *(bf16x4*)&WT[(size_t)(bx * 64 + n) * K + by * 64 + c4] = o;
    }
}

__global__ __launch_bounds__(256)
void prep(const float* __restrict__ x, short* __restrict__ xb,
          const float* __restrict__ qkv_w, short* __restrict__ qwt,
          const float* __restrict__ out_w, short* __restrict__ owt,
          unsigned* __restrict__ bar)
{
    __shared__ float t[64][65];
    const int b = blockIdx.x;
    const int tid = threadIdx.x;
    if (b == 0) {                      // re-arm grid barrier (3 x 128 slots)
        bar[tid] = 0u;
        if (tid < 128) bar[256 + tid] = 0u;
    }
    if (b < 2048) {
        const int i = b * 256 + tid;
        const floatx4 a = *(const floatx4*)(x + (size_t)i * 8);
        const floatx4 c = *(const floatx4*)(x + (size_t)i * 8 + 4);
        bf16x8 o;
        o[0] = f2bf(a[0]); o[1] = f2bf(a[1]); o[2] = f2bf(a[2]); o[3] = f2bf(a[3]);
        o[4] = f2bf(c[0]); o[5] = f2bf(c[1]); o[6] = f2bf(c[2]); o[7] = f2bf(c[3]);
        *(bf16x8*)(xb + (size_t)i * 8) = o;
    } else if (b < 2048 + 768) {
        const int u = b - 2048;
        transpose_tile(qkv_w, qwt, EMB, N3, u % 48, u / 48, t, tid);
    } else {
        const int u = b - 2816;
        transpose_tile(out_w, owt, EMB, EMB, u & 15, u >> 4, t, tid);
    }
}

// ---------------------------------------------------------------------------
// K1: qkv GEMM — 256x256 tile, BK=64, 8 waves (2Mx4N), 8-phase schedule.
// (unchanged — verified correct in R2)
// ---------------------------------------------------------------------------
#define MFMA16 __builtin_amdgcn_mfma_f32_16x16x32_bf16

__global__ __launch_bounds__(512, 2)
void mfma_gemm_qkv256(const short* __restrict__ A, const short* __restrict__ BT,
                      const float* __restrict__ bias,
                      short* __restrict__ OQ, short* __restrict__ OK,
                      short* __restrict__ OV)
{
    __shared__ __align__(16) short lds[65536];   // 128 KiB
    const int tid  = threadIdx.x;
    const int lane = tid & 63;
    const int wave = tid >> 6;           // 0..7
    const int wr   = wave >> 2;          // 0..1 (M half)
    const int wc   = wave & 3;           // 0..3 (N quarter)
    const int frow = lane & 15;
    const int quad = lane >> 4;
    const int q8   = quad * 8;
    const int bx = blockIdx.x;           // N tiles: 12
    const int by = blockIdx.y;           // M tiles: 16

    const short* Ab = A  + (size_t)(by * 256) * 1024;
    const short* Bb = BT + (size_t)(bx * 256) * 1024;

    const int trow = tid >> 3;
    const int ccol = (tid & 7) * 8;
    const int scol = ccol ^ ((trow & 12) << 2);
    const int sx = (frow & 12) << 2;
    const int wcb = wc * 64 + frow;

#define STG(LBASE, GPTR) do {                                               \
        const short* g_ = (GPTR);                                           \
        _Pragma("unroll")                                                   \
        for (int j_ = 0; j_ < 2; ++j_) {                                    \
            const int r_ = j_ * 64 + trow;                                  \
            gload_lds16(g_ + (size_t)r_ * 1024 + scol,                      \
                        &lds[(LBASE) + r_ * 64 + ccol]);                    \
        }                                                                   \
    } while (0)

#define LDA(BASE, R, KS) \
    (*(const bf16x8*)&lds[(BASE) + (R) * 64 + ((((KS) * 32) + q8) ^ sx)])

    floatx4 acc[8][4] = {};
    bf16x8  bq[4][2];

#define PHASE(ABASE, BBASE, QD, RDB, VM, ...) do {                          \
        const int Rr_ = wr * 128 + (QD) * 32 + frow;                        \
        bf16x8 a0_ = LDA((ABASE), Rr_,      0);                             \
        bf16x8 a1_ = LDA((ABASE), Rr_,      1);                             \
        bf16x8 a2_ = LDA((ABASE), Rr_ + 16, 0);                             \
        bf16x8 a3_ = LDA((ABASE), Rr_ + 16, 1);                             \
        if (RDB) {                                                          \
            _Pragma("unroll")                                               \
            for (int ni_ = 0; ni_ < 4; ++ni_) {                             \
                bq[ni_][0] = LDA((BBASE), wcb + ni_ * 16, 0);               \
                bq[ni_][1] = LDA((BBASE), wcb + ni_ * 16, 1);               \
            }                                                               \
        }                                                                   \
        __VA_ARGS__;                                                        \
        __builtin_amdgcn_sched_barrier(0);                                  \
        __builtin_amdgcn_s_barrier();                                       \
        asm volatile("s_waitcnt lgkmcnt(0)" ::: "memory");                  \
        __builtin_amdgcn_sched_barrier(0);                                  \
        __builtin_amdgcn_s_setprio(1);                                      \
        _Pragma("unroll")                                                   \
        for (int ni_ = 0; ni_ < 4; ++ni_) {                                 \
            acc[2*(QD)  ][ni_] = MFMA16(a0_, bq[ni_][0], acc[2*(QD)  ][ni_], 0,0,0); \
            acc[2*(QD)  ][ni_] = MFMA16(a1_, bq[ni_][1], acc[2*(QD)  ][ni_], 0,0,0); \
            acc[2*(QD)+1][ni_] = MFMA16(a2_, bq[ni_][0], acc[2*(QD)+1][ni_], 0,0,0); \
            acc[2*(QD)+1][ni_] = MFMA16(a3_, bq[ni_][1], acc[2*(QD)+1][ni_], 0,0,0); \
        }                                                                   \
        __builtin_amdgcn_s_setprio(0);                                      \
        if (VM) asm volatile("s_waitcnt vmcnt(4)" ::: "memory");            \
        __builtin_amdgcn_s_barrier();                                       \
        __builtin_amdgcn_sched_barrier(0);                                  \
    } while (0)

    STG(0,     Ab);
    STG(8192,  Ab + 131072);
    STG(16384, Bb);
    STG(24576, Bb + 131072);
    STG(49152, Bb + 64);
    STG(57344, Bb + 131072 + 64);
    asm volatile("s_waitcnt vmcnt(4)" ::: "memory");
    __builtin_amdgcn_s_barrier();
    __builtin_amdgcn_sched_barrier(0);

#pragma unroll 1
    for (int it = 0; it < 8; ++it) {
        const int k1  = (2 * it + 1) * 64;
        const int kn0 = ((2 * it + 2) & 15) * 64;
        const int kn1 = ((2 * it + 3) & 15) * 64;

        PHASE(0, 16384, 0, 1, 0,
              STG(32768, Ab + k1); STG(40960, Ab + 131072 + k1));
        PHASE(0, 16384, 1, 0, 0, STG(16384, Bb + kn0));
        PHASE(0, 16384, 2, 0, 0, STG(24576, Bb + 131072 + kn0));
        PHASE(0, 16384, 3, 0, 1, ((void)0));
        PHASE(32768, 49152, 0, 1, 0, STG(0,    Ab + kn0));
        PHASE(32768, 49152, 1, 0, 0, STG(8192, Ab + 131072 + kn0));
        PHASE(32768, 49152, 2, 0, 0, STG(49152, Bb + kn1));
        PHASE(32768, 49152, 3, 0, 1, STG(57344, Bb + 131072 + kn1));
    }

    __syncthreads();

    const int wbase = wave * 8192;
    const int colg0 = bx * 256 + wc * 64;
    const int rsel  = colg0 >> 10;
    const bool do_elu = rsel < 2;
    short* obase = (rsel == 0) ? OQ : (rsel == 1 ? OK : OV);
    const int h  = (colg0 >> 6) & 15;
    const int L0 = by * 256 + wr * 128;
#pragma unroll
    for (int ni = 0; ni < 4; ++ni) {
        const float bv = bias[colg0 + ni * 16 + frow];
#pragma unroll
        for (int mi = 0; mi < 8; ++mi)
#pragma unroll
            for (int r = 0; r < 4; ++r) {
                float v = acc[mi][ni][r] + bv;
                if (do_elu) v = (v > 0.f) ? (v + 1.f) : __expf(v);
                lds[wbase + (mi * 16 + quad * 4 + r) * 64 + ni * 16 + frow] = f2bf(v);
            }
    }
#pragma unroll
    for (int s = 0; s < 16; ++s) {
        const int chunk = s * 64 + lane;
        const int row = chunk >> 3, c8 = (chunk & 7) * 8;
        *(bf16x8*)&obase[((size_t)(h * L_SEQ + L0 + row)) * HD + c8] =
            *(const bf16x8*)&lds[wbase + row * 64 + c8];
    }
#undef PHASE
#undef LDA
#undef STG
}

// ---------------------------------------------------------------------------
// K2: fused tail — 4 phases, fence-free grid barriers, 1024 blocks x 256.
// Phase-crossing writes (ScTb, zc, S0b, attnb) use sc1 agent-scope stores
// (coherent at IF); readers first-touch after the barrier -> plain loads OK.
// ---------------------------------------------------------------------------
#define SP 72

__global__ __launch_bounds__(256, 4)
void tail(const short* __restrict__ Qb, const short* __restrict__ Kb,
          const short* __restrict__ Vb,
          short* __restrict__ ScTb, float* __restrict__ zc,
          short* __restrict__ S0b, short* __restrict__ attnb,
          const short* __restrict__ owt, const float* __restrict__ out_b,
          float* __restrict__ out, unsigned* __restrict__ bar)
{
    __shared__ __align__(16) short shm[12288];
    const int tid  = threadIdx.x;
    const int lane = tid & 63;
    const int wave = tid >> 6;
    const int bidf = blockIdx.y * 64 + blockIdx.x;   // 0..1023
    const int frow = lane & 15;
    const int quad = lane >> 4;
    const int fko  = quad << 3;

    // ---------------- phase 1: chunk_state ----------------
    {
        short* Vt = shm;                 // 64 x SP
        short* Kt = shm + 64 * SP;       // 64 x SP
        const int c = blockIdx.x, h = blockIdx.y;
        const int wm = wave << 4;
        const short* Kg = Kb + ((size_t)h * L_SEQ + (size_t)c * CHUNK) * HD;
        const short* Vg = Vb + ((size_t)h * L_SEQ + (size_t)c * CHUNK) * HD;

#pragma unroll
        for (int q = 0; q < 2; ++q) {
            const int idx = q * 256 + tid;
            const int l = idx >> 3, c8 = (idx & 7) << 3;
            const bf16x8 vv = *(const bf16x8*)&Vg[l * 64 + c8];
            const bf16x8 kk = *(const bf16x8*)&Kg[l * 64 + c8];
#pragma unroll
            for (int j = 0; j < 8; ++j) {
                Vt[(c8 + j) * SP + l] = vv[j];
                Kt[(c8 + j) * SP + l] = kk[j];
            }
        }
        __syncthreads();

        const bf16x8 af0 = *(const bf16x8*)&Vt[(wm + frow) * SP + fko];
        const bf16x8 af1 = *(const bf16x8*)&Vt[(wm + frow) * SP + 32 + fko];

        floatx4 acc[4] = {};
#pragma unroll
        for (int n = 0; n < 4; ++n) {
            const bf16x8 kf0 = *(const bf16x8*)&Kt[(n * 16 + frow) * SP + fko];
            const bf16x8 kf1 = *(const bf16x8*)&Kt[(n * 16 + frow) * SP + 32 + fko];
            acc[n] = MFMA16(af0, kf0, acc[n], 0, 0, 0);
            acc[n] = MFMA16(af1, kf1, acc[n], 0, 0, 0);
        }

        // sc1 stores, u32-packed via lane-pairing (d = n*16+frow, pairs d,d+1)
        short* Sout = ScTb + (size_t)(h * NCHUNK + c) * 4096;
#pragma unroll
        for (int n = 0; n < 4; ++n)
#pragma unroll
            for (int r = 0; r < 4; ++r) {
                const int e = wm + quad * 4 + r;
                const int d = n * 16 + frow;
                const unsigned lo = (unsigned short)f2bf(acc[n][r]);
                const unsigned hi = (unsigned)__shfl_down((int)lo, 1);
                if (!(frow & 1))
                    cstore_u32(&Sout[e * 64 + d], lo | (hi << 16));
            }

        if (wave == 0) {
            bf16x8 ones;
#pragma unroll
            for (int j = 0; j < 8; ++j) ones[j] = (short)0x3F80;
            floatx4 zacc[4] = {};
#pragma unroll
            for (int n = 0; n < 4; ++n) {
                const bf16x8 kf0 = *(const bf16x8*)&Kt[(n * 16 + frow) * SP + fko];
                const bf16x8 kf1 = *(const bf16x8*)&Kt[(n * 16 + frow) * SP + 32 + fko];
                zacc[n] = MFMA16(ones, kf0, zacc[n], 0, 0, 0);
                zacc[n] = MFMA16(ones, kf1, zacc[n], 0, 0, 0);
            }
            if (quad == 0) {
#pragma unroll
                for (int n = 0; n < 4; ++n)
                    cstore_f32(&zc[(size_t)(h * NCHUNK + c) * 64 + n * 16 + frow],
                               zacc[n][0]);
            }
        }
    }
    gbar(bar, tid, bidf, 0);

    // ---------------- phase 2: prefix scan (blocks 0..255) ----------------
    if (bidf < 256) {
        const int g = bidf * 256 + tid;
        const int h  = g >> 12;
        const int ed = g & 4095;
        const int e  = ed >> 6;
        const int d  = ed & 63;          // == lane; pairs (d, d+1) in-wave
        const short* src = ScTb + (size_t)h * NCHUNK * 4096 + ed;
        float run = 0.f;
        for (int cb = 0; cb < NCHUNK; cb += 8) {
            short v[8];
#pragma unroll
            for (int u = 0; u < 8; ++u) v[u] = src[(size_t)(cb + u) * 4096];
#pragma unroll
            for (int u = 0; u < 8; ++u) {
                const unsigned lo = (unsigned short)f2bf(run);
                const unsigned hi = (unsigned)__shfl_down((int)lo, 1);
                if (!(d & 1))
                    cstore_u32(&S0b[((size_t)((h * NCHUNK + cb + u) * 65 + e)) * 64 + d],
                               lo | (hi << 16));
                run += bf2f(v[u]);
            }
        }
        if (g < NH * HD) {
            const int h2 = g >> 6, d2 = g & 63;
            float rz = 0.f;
            for (int cb = 0; cb < NCHUNK; cb += 8) {
                float w[8];
#pragma unroll
                for (int u = 0; u < 8; ++u)
                    w[u] = zc[((size_t)(h2 * NCHUNK + cb + u)) * HD + d2];
#pragma unroll
                for (int u = 0; u < 8; ++u) {
                    const unsigned lo = (unsigned short)f2bf(rz);
                    const unsigned hi = (unsigned)__shfl_down((int)lo, 1);
                    if (!(d2 & 1))
                        cstore_u32(&S0b[((size_t)((h2 * NCHUNK + cb + u) * 65 + 64)) * 64 + d2],
                                   lo | (hi << 16));
                    rz += w[u];
                }
            }
        }
    }
    gbar(bar, tid, bidf, 1);

    // ---------------- phase 3: chunk_attn ----------------
    {
        short* Vs = shm;                 // 65 x SP (row 64 = ones)
        short* As = shm + 65 * SP;       // 64 x SP
        const int c = blockIdx.x, h = blockIdx.y;
        const int wm = wave << 4;
        const size_t rb = ((size_t)h * L_SEQ + (size_t)c * CHUNK) * HD;
        const short* Qg = Qb + rb;
        const short* Kg = Kb + rb;
        const short* Vg = Vb + rb;
        const short* Sg = S0b + (size_t)(h * NCHUNK + c) * 65 * 64;

#pragma unroll
        for (int q = 0; q < 2; ++q) {
            const int idx = q * 256 + tid;
            const int row = idx >> 3, c8 = (idx & 7) << 3;
            const bf16x8 vv = *(const bf16x8*)&Vg[row * 64 + c8];
#pragma unroll
            for (int j = 0; j < 8; ++j) Vs[(c8 + j) * SP + row] = vv[j];
        }
        if (tid < 64) Vs[64 * SP + tid] = (short)0x3F80;
        __syncthreads();

        const bf16x8 qf0 = *(const bf16x8*)&Qg[(wm + frow) * 64 + fko];
        const bf16x8 qf1 = *(const bf16x8*)&Qg[(wm + frow) * 64 + 32 + fko];

        floatx4 sacc[4] = {};
#pragma unroll
        for (int n = 0; n < 4; ++n) {
            const bf16x8 kf0 = *(const bf16x8*)&Kg[(n * 16 + frow) * 64 + fko];
            const bf16x8 kf1 = *(const bf16x8*)&Kg[(n * 16 + frow) * 64 + 32 + fko];
            sacc[n] = MFMA16(qf0, kf0, sacc[n], 0, 0, 0);
            sacc[n] = MFMA16(qf1, kf1, sacc[n], 0, 0, 0);
        }
#pragma unroll
        for (int n = 0; n < 4; ++n)
#pragma unroll
            for (int r = 0; r < 4; ++r) {
                const int i = wm + quad * 4 + r;
                const int j = n * 16 + frow;
                As[i * SP + j] = (j <= i) ? f2bf(sacc[n][r]) : (short)0;
            }
        const bf16x8 af0 = *(const bf16x8*)&As[(wm + frow) * SP + fko];
        const bf16x8 af1 = *(const bf16x8*)&As[(wm + frow) * SP + 32 + fko];

        floatx4 oacc[5] = {};
#pragma unroll
        for (int n = 0; n < 4; ++n) {
            const bf16x8 vf0 = *(const bf16x8*)&Vs[(n * 16 + frow) * SP + fko];
            const bf16x8 vf1 = *(const bf16x8*)&Vs[(n * 16 + frow) * SP + 32 + fko];
            oacc[n] = MFMA16(af0, vf0, oacc[n], 0, 0, 0);
            oacc[n] = MFMA16(af1, vf1, oacc[n], 0, 0, 0);
            const bf16x8 sf0 = *(const bf16x8*)&Sg[(n * 16 + frow) * 64 + fko];
            const bf16x8 sf1 = *(const bf16x8*)&Sg[(n * 16 + frow) * 64 + 32 + fko];
            oacc[n] = MFMA16(qf0, sf0, oacc[n], 0, 0, 0);
            oacc[n] = MFMA16(qf1, sf1, oacc[n], 0, 0, 0);
        }
        {
            const bf16x8 vf0 = *(const bf16x8*)&Vs[64 * SP + fko];
            const bf16x8 vf1 = *(const bf16x8*)&Vs[64 * SP + 32 + fko];
            oacc[4] = MFMA16(af0, vf0, oacc[4], 0, 0, 0);
            oacc[4] = MFMA16(af1, vf1, oacc[4], 0, 0, 0);
            const bf16x8 sf0 = *(const bf16x8*)&Sg[64 * 64 + fko];
            const bf16x8 sf1 = *(const bf16x8*)&Sg[64 * 64 + 32 + fko];
            oacc[4] = MFMA16(qf0, sf0, oacc[4], 0, 0, 0);
            oacc[4] = MFMA16(qf1, sf1, oacc[4], 0, 0, 0);
        }
#pragma unroll
        for (int r = 0; r < 4; ++r) {
            const float norm = __shfl(oacc[4][r], lane & 48) + EPS;
            const float inv = 1.f / norm;
            const int i = wm + quad * 4 + r;
#pragma unroll
            for (int n = 0; n < 4; ++n)
                As[i * SP + n * 16 + frow] = f2bf(oacc[n][r] * inv);
        }
        __syncthreads();
#pragma unroll
        for (int t = 0; t < 2; ++t) {
            const int idx = t * 256 + tid;
            const int row = idx >> 3, c8 = (idx & 7) << 3;
            union { bf16x8 v; unsigned long long q[2]; } uu;
            uu.v = *(const bf16x8*)&As[row * SP + c8];
            unsigned long long* dst = (unsigned long long*)
                &attnb[(size_t)(c * CHUNK + row) * EMB + h * HD + c8];
            cstore_u64(dst,     uu.q[0]);
            cstore_u64(dst + 1, uu.q[1]);
        }
    }
    gbar(bar, tid, bidf, 2);

    // ---------------- phase 4: out GEMM (blocks 0..511) ----------------
    if (bidf < 512) {
        short* smem = shm;
        short* pan[4] = { smem, smem + 2048, smem + 6144, smem + 8192 };
        const int wm = (wave >> 1) * 32;
        const int wn = (wave & 1) * 64;
        const int bx = bidf & 7;
        const int by = bidf >> 3;

        const short* Ab = attnb + (size_t)(by * 64) * 1024;
        const short* Bb = owt   + (size_t)(bx * 128) * 1024;

        floatx4 acc[2][4] = {};

        for (int k0 = 0; k0 < 1024; k0 += 64) {
#pragma unroll
            for (int p = 0; p < 2; ++p) {
                const int kp = k0 + p * 32;
                {
                    const int row = tid >> 2;
                    const int kc  = (tid & 3) << 3;
                    gload_lds16(Ab + (size_t)row * 1024 + kp + kc, &pan[p * 2 + 0][tid << 3]);
                }
#pragma unroll
                for (int q = 0; q < 2; ++q) {
                    const int ib = q * 256 + tid;
                    const int row = ib >> 2;
                    const int kc  = (ib & 3) << 3;
                    gload_lds16(Bb + (size_t)row * 1024 + kp + kc, &pan[p * 2 + 1][ib << 3]);
                }
            }
            __syncthreads();
#pragma unroll
            for (int p = 0; p < 2; ++p) {
                bf16x8 af[2], bfv[4];
#pragma unroll
                for (int mi = 0; mi < 2; ++mi)
                    af[mi] = *(const bf16x8*)&pan[p * 2 + 0][(wm + mi * 16 + frow) * 32 + fko];
#pragma unroll
                for (int ni = 0; ni < 4; ++ni)
                    bfv[ni] = *(const bf16x8*)&pan[p * 2 + 1][(wn + ni * 16 + frow) * 32 + fko];
#pragma unroll
                for (int mi = 0; mi < 2; ++mi)
#pragma unroll
                    for (int ni = 0; ni < 4; ++ni)
                        acc[mi][ni] = MFMA16(af[mi], bfv[ni], acc[mi][ni], 0, 0, 0);
            }
            __syncthreads();
        }

        const int rq = quad << 2;
#pragma unroll
        for (int ni = 0; ni < 4; ++ni) {
            const int n = bx * 128 + wn + ni * 16 + frow;
            const float bv = out_b[n];
#pragma unroll
            for (int mi = 0; mi < 2; ++mi)
#pragma unroll
                for (int r = 0; r < 4; ++r) {
                    const int m = by * 64 + wm + mi * 16 + rq + r;
                    out[(size_t)m * 1024 + n] = acc[mi][ni][r] + bv;
                }
        }
    }
}

// ---------------------------------------------------------------------------
extern "C" void kernel_launch(void* const* d_in, const int* in_sizes, int n_in,
                              void* d_out, int out_size, void* d_ws, size_t ws_size,
                              hipStream_t stream)
{
    const float* x     = (const float*)d_in[0];
    const float* qkv_w = (const float*)d_in[1];
    const float* qkv_b = (const float*)d_in[2];
    const float* out_w = (const float*)d_in[3];
    const float* out_b = (const float*)d_in[4];
    float* out = (float*)d_out;

    short* ws    = (short*)d_ws;
    short* Qb    = ws;                   // head-major bf16, 4194304 each
    short* Kb    = Qb + 4194304;
    short* Vb    = Kb + 4194304;
    short* xb    = Vb + 4194304;
    short* qwt   = xb + 4194304;         // 3072 x 1024
    short* owt   = qwt + 3145728;        // 1024 x 1024
    short* attnb = owt + 1048576;        // 4096 x 1024
    short* ScTb  = attnb + 4194304;      // 1024 * 64 * 64
    short* S0b   = ScTb + 4194304;       // 1024 * 65 * 64
    float* zc    = (float*)(S0b + 4259840);    // 65536 fp32
    unsigned* bar = (unsigned*)(zc + 65536);   // 3 x 128 barrier slots

    prep<<<dim3(3072), 256, 0, stream>>>(x, xb, qkv_w, qwt, out_w, owt, bar);
    mfma_gemm_qkv256<<<dim3(N3 / 256, L_SEQ / 256), 512, 0, stream>>>(
        xb, qwt, qkv_b, Qb, Kb, Vb);
    tail<<<dim3(NCHUNK, NH), 256, 0, stream>>>(
        Qb, Kb, Vb, ScTb, zc, S0b, attnb, owt, out_b, out, bar);
}

// Round 5
// 165.239 us; speedup vs baseline: 2.6018x; 1.2812x over previous
//
#include <hip/hip_runtime.h>
#include <cstddef>
#include <cstdint>

#define L_SEQ 4096
#define EMB   1024
#define NH    16
#define HD    64
#define N3    3072
#define CHUNK 64
#define NCHUNK 64
#define EPS 1e-6f

typedef __attribute__((ext_vector_type(8))) short   bf16x8;
typedef __attribute__((ext_vector_type(4))) short   bf16x4;
typedef __attribute__((ext_vector_type(4))) float   floatx4;

#define AS1 __attribute__((address_space(1)))
#define AS3 __attribute__((address_space(3)))

__device__ __forceinline__ void gload_lds16(const void* g, void* l) {
    __builtin_amdgcn_global_load_lds((AS1 const unsigned int*)g,
                                     (AS3 unsigned int*)l, 16, 0, 0);
}

// round-to-nearest-even fp32 -> bf16 bits
__device__ __forceinline__ short f2bf(float f) {
    union { float f; unsigned u; } a; a.f = f;
    unsigned r = a.u + 0x7fffu + ((a.u >> 16) & 1u);
    return (short)(r >> 16);
}
__device__ __forceinline__ float bf2f(short s) {
    union { unsigned u; float f; } a; a.u = ((unsigned)(unsigned short)s) << 16;
    return a.f;
}

// ---------------------------------------------------------------------------
// K0: fused prep — blocks [0,2048): x->bf16; [2048,2816): qkv_w^T;
// [2816,3072): out_w^T.
// ---------------------------------------------------------------------------
__device__ __forceinline__ void transpose_tile(const float* __restrict__ W,
                                               short* __restrict__ WT,
                                               int K, int N, int bx, int by,
                                               float (*t)[65], int tid)
{
    const int r  = tid >> 4;
    const int c4 = (tid & 15) << 2;
#pragma unroll
    for (int s = 0; s < 4; ++s) {
        const int k = r + s * 16;
        const floatx4 v = *(const floatx4*)&W[(size_t)(by * 64 + k) * N + bx * 64 + c4];
        t[k][c4 + 0] = v[0]; t[k][c4 + 1] = v[1];
        t[k][c4 + 2] = v[2]; t[k][c4 + 3] = v[3];
    }
    __syncthreads();
#pragma unroll
    for (int s = 0; s < 4; ++s) {
        const int n = r + s * 16;
        bf16x4 o;
        o[0] = f2bf(t[c4 + 0][n]); o[1] = f2bf(t[c4 + 1][n]);
        o[2] = f2bf(t[c4 + 2][n]); o[3] = f2bf(t[c4 + 3][n]);
        *(bf16x4*)&WT[(size_t)(bx * 64 + n) * K + by * 64 + c4] = o;
    }
}

__global__ __launch_bounds__(256)
void prep(const float* __restrict__ x, short* __restrict__ xb,
          const float* __restrict__ qkv_w, short* __restrict__ qwt,
          const float* __restrict__ out_w, short* __restrict__ owt)
{
    __shared__ float t[64][65];
    const int b = blockIdx.x;
    const int tid = threadIdx.x;
    if (b < 2048) {
        const int i = b * 256 + tid;
        const floatx4 a = *(const floatx4*)(x + (size_t)i * 8);
        const floatx4 c = *(const floatx4*)(x + (size_t)i * 8 + 4);
        bf16x8 o;
        o[0] = f2bf(a[0]); o[1] = f2bf(a[1]); o[2] = f2bf(a[2]); o[3] = f2bf(a[3]);
        o[4] = f2bf(c[0]); o[5] = f2bf(c[1]); o[6] = f2bf(c[2]); o[7] = f2bf(c[3]);
        *(bf16x8*)(xb + (size_t)i * 8) = o;
    } else if (b < 2048 + 768) {
        const int u = b - 2048;
        transpose_tile(qkv_w, qwt, EMB, N3, u % 48, u / 48, t, tid);
    } else {
        const int u = b - 2816;
        transpose_tile(out_w, owt, EMB, EMB, u & 15, u >> 4, t, tid);
    }
}

// ---------------------------------------------------------------------------
// K1: qkv GEMM — 256x256 tile, BK=64, 8 waves (2Mx4N), 8-phase schedule.
// (unchanged — verified correct in R2/R4)
// ---------------------------------------------------------------------------
#define MFMA16 __builtin_amdgcn_mfma_f32_16x16x32_bf16

__global__ __launch_bounds__(512, 2)
void mfma_gemm_qkv256(const short* __restrict__ A, const short* __restrict__ BT,
                      const float* __restrict__ bias,
                      short* __restrict__ OQ, short* __restrict__ OK,
                      short* __restrict__ OV)
{
    __shared__ __align__(16) short lds[65536];   // 128 KiB
    const int tid  = threadIdx.x;
    const int lane = tid & 63;
    const int wave = tid >> 6;           // 0..7
    const int wr   = wave >> 2;          // 0..1 (M half)
    const int wc   = wave & 3;           // 0..3 (N quarter)
    const int frow = lane & 15;
    const int quad = lane >> 4;
    const int q8   = quad * 8;
    const int bx = blockIdx.x;           // N tiles: 12
    const int by = blockIdx.y;           // M tiles: 16

    const short* Ab = A  + (size_t)(by * 256) * 1024;
    const short* Bb = BT + (size_t)(bx * 256) * 1024;

    const int trow = tid >> 3;
    const int ccol = (tid & 7) * 8;
    const int scol = ccol ^ ((trow & 12) << 2);
    const int sx = (frow & 12) << 2;
    const int wcb = wc * 64 + frow;

#define STG(LBASE, GPTR) do {                                               \
        const short* g_ = (GPTR);                                           \
        _Pragma("unroll")                                                   \
        for (int j_ = 0; j_ < 2; ++j_) {                                    \
            const int r_ = j_ * 64 + trow;                                  \
            gload_lds16(g_ + (size_t)r_ * 1024 + scol,                      \
                        &lds[(LBASE) + r_ * 64 + ccol]);                    \
        }                                                                   \
    } while (0)

#define LDA(BASE, R, KS) \
    (*(const bf16x8*)&lds[(BASE) + (R) * 64 + ((((KS) * 32) + q8) ^ sx)])

    floatx4 acc[8][4] = {};
    bf16x8  bq[4][2];

#define PHASE(ABASE, BBASE, QD, RDB, VM, ...) do {                          \
        const int Rr_ = wr * 128 + (QD) * 32 + frow;                        \
        bf16x8 a0_ = LDA((ABASE), Rr_,      0);                             \
        bf16x8 a1_ = LDA((ABASE), Rr_,      1);                             \
        bf16x8 a2_ = LDA((ABASE), Rr_ + 16, 0);                             \
        bf16x8 a3_ = LDA((ABASE), Rr_ + 16, 1);                             \
        if (RDB) {                                                          \
            _Pragma("unroll")                                               \
            for (int ni_ = 0; ni_ < 4; ++ni_) {                             \
                bq[ni_][0] = LDA((BBASE), wcb + ni_ * 16, 0);               \
                bq[ni_][1] = LDA((BBASE), wcb + ni_ * 16, 1);               \
            }                                                               \
        }                                                                   \
        __VA_ARGS__;                                                        \
        __builtin_amdgcn_sched_barrier(0);                                  \
        __builtin_amdgcn_s_barrier();                                       \
        asm volatile("s_waitcnt lgkmcnt(0)" ::: "memory");                  \
        __builtin_amdgcn_sched_barrier(0);                                  \
        __builtin_amdgcn_s_setprio(1);                                      \
        _Pragma("unroll")                                                   \
        for (int ni_ = 0; ni_ < 4; ++ni_) {                                 \
            acc[2*(QD)  ][ni_] = MFMA16(a0_, bq[ni_][0], acc[2*(QD)  ][ni_], 0,0,0); \
            acc[2*(QD)  ][ni_] = MFMA16(a1_, bq[ni_][1], acc[2*(QD)  ][ni_], 0,0,0); \
            acc[2*(QD)+1][ni_] = MFMA16(a2_, bq[ni_][0], acc[2*(QD)+1][ni_], 0,0,0); \
            acc[2*(QD)+1][ni_] = MFMA16(a3_, bq[ni_][1], acc[2*(QD)+1][ni_], 0,0,0); \
        }                                                                   \
        __builtin_amdgcn_s_setprio(0);                                      \
        if (VM) asm volatile("s_waitcnt vmcnt(4)" ::: "memory");            \
        __builtin_amdgcn_s_barrier();                                       \
        __builtin_amdgcn_sched_barrier(0);                                  \
    } while (0)

    STG(0,     Ab);
    STG(8192,  Ab + 131072);
    STG(16384, Bb);
    STG(24576, Bb + 131072);
    STG(49152, Bb + 64);
    STG(57344, Bb + 131072 + 64);
    asm volatile("s_waitcnt vmcnt(4)" ::: "memory");
    __builtin_amdgcn_s_barrier();
    __builtin_amdgcn_sched_barrier(0);

#pragma unroll 1
    for (int it = 0; it < 8; ++it) {
        const int k1  = (2 * it + 1) * 64;
        const int kn0 = ((2 * it + 2) & 15) * 64;
        const int kn1 = ((2 * it + 3) & 15) * 64;

        PHASE(0, 16384, 0, 1, 0,
              STG(32768, Ab + k1); STG(40960, Ab + 131072 + k1));
        PHASE(0, 16384, 1, 0, 0, STG(16384, Bb + kn0));
        PHASE(0, 16384, 2, 0, 0, STG(24576, Bb + 131072 + kn0));
        PHASE(0, 16384, 3, 0, 1, ((void)0));
        PHASE(32768, 49152, 0, 1, 0, STG(0,    Ab + kn0));
        PHASE(32768, 49152, 1, 0, 0, STG(8192, Ab + 131072 + kn0));
        PHASE(32768, 49152, 2, 0, 0, STG(49152, Bb + kn1));
        PHASE(32768, 49152, 3, 0, 1, STG(57344, Bb + 131072 + kn1));
    }

    __syncthreads();

    const int wbase = wave * 8192;
    const int colg0 = bx * 256 + wc * 64;
    const int rsel  = colg0 >> 10;
    const bool do_elu = rsel < 2;
    short* obase = (rsel == 0) ? OQ : (rsel == 1 ? OK : OV);
    const int h  = (colg0 >> 6) & 15;
    const int L0 = by * 256 + wr * 128;
#pragma unroll
    for (int ni = 0; ni < 4; ++ni) {
        const float bv = bias[colg0 + ni * 16 + frow];
#pragma unroll
        for (int mi = 0; mi < 8; ++mi)
#pragma unroll
            for (int r = 0; r < 4; ++r) {
                float v = acc[mi][ni][r] + bv;
                if (do_elu) v = (v > 0.f) ? (v + 1.f) : __expf(v);
                lds[wbase + (mi * 16 + quad * 4 + r) * 64 + ni * 16 + frow] = f2bf(v);
            }
    }
#pragma unroll
    for (int s = 0; s < 16; ++s) {
        const int chunk = s * 64 + lane;
        const int row = chunk >> 3, c8 = (chunk & 7) * 8;
        *(bf16x8*)&obase[((size_t)(h * L_SEQ + L0 + row)) * HD + c8] =
            *(const bf16x8*)&lds[wbase + row * 64 + c8];
    }
#undef PHASE
#undef LDA
#undef STG
}

// ---------------------------------------------------------------------------
// K5: out-projection GEMM, 64x128 tile (512 blocks = 2/CU), double-panel.
// ---------------------------------------------------------------------------
__global__ __launch_bounds__(256)
void mfma_gemm_out(const short* __restrict__ A, const short* __restrict__ BT,
                   const float* __restrict__ bias, float* __restrict__ OF,
                   int N, int K)
{
    __shared__ __align__(16) short smem[12288];
    short* pan[4] = { smem, smem + 2048, smem + 6144, smem + 8192 };
    const int tid  = threadIdx.x;
    const int lane = tid & 63;
    const int wave = tid >> 6;
    const int wm = (wave >> 1) * 32;
    const int wn = (wave & 1) * 64;
    const int bx = blockIdx.x;
    const int by = blockIdx.y;
    const int frow = lane & 15;
    const int quad = lane >> 4;
    const int fko  = quad << 3;

    const short* Ab = A  + (size_t)(by * 64) * K;
    const short* Bb = BT + (size_t)(bx * 128) * K;

    floatx4 acc[2][4] = {};

    for (int k0 = 0; k0 < K; k0 += 64) {
#pragma unroll
        for (int p = 0; p < 2; ++p) {
            const int kp = k0 + p * 32;
            {
                const int row = tid >> 2;
                const int kc  = (tid & 3) << 3;
                gload_lds16(Ab + (size_t)row * K + kp + kc, &pan[p * 2 + 0][tid << 3]);
            }
#pragma unroll
            for (int q = 0; q < 2; ++q) {
                const int ib = q * 256 + tid;
                const int row = ib >> 2;
                const int kc  = (ib & 3) << 3;
                gload_lds16(Bb + (size_t)row * K + kp + kc, &pan[p * 2 + 1][ib << 3]);
            }
        }
        __syncthreads();
#pragma unroll
        for (int p = 0; p < 2; ++p) {
            bf16x8 af[2], bfv[4];
#pragma unroll
            for (int mi = 0; mi < 2; ++mi)
                af[mi] = *(const bf16x8*)&pan[p * 2 + 0][(wm + mi * 16 + frow) * 32 + fko];
#pragma unroll
            for (int ni = 0; ni < 4; ++ni)
                bfv[ni] = *(const bf16x8*)&pan[p * 2 + 1][(wn + ni * 16 + frow) * 32 + fko];
#pragma unroll
            for (int mi = 0; mi < 2; ++mi)
#pragma unroll
                for (int ni = 0; ni < 4; ++ni)
                    acc[mi][ni] = __builtin_amdgcn_mfma_f32_16x16x32_bf16(
                        af[mi], bfv[ni], acc[mi][ni], 0, 0, 0);
        }
        __syncthreads();
    }

    const int rq = quad << 2;
#pragma unroll
    for (int ni = 0; ni < 4; ++ni) {
        const int n = bx * 128 + wn + ni * 16 + frow;
        const float bv = bias[n];
#pragma unroll
        for (int mi = 0; mi < 2; ++mi)
#pragma unroll
            for (int r = 0; r < 4; ++r) {
                const int m = by * 64 + wm + mi * 16 + rq + r;
                OF[(size_t)m * N + n] = acc[mi][ni][r] + bv;
            }
    }
}

// ---------------------------------------------------------------------------
// K2: per-(head,chunk) state sums, MFMA version. (unchanged)
// ---------------------------------------------------------------------------
#define SP 72

__global__ __launch_bounds__(256, 4)
void chunk_state(const short* __restrict__ Kb, const short* __restrict__ Vb,
                 short* __restrict__ ScTb, float* __restrict__ zc)
{
    __shared__ __align__(16) short Vt[64 * SP];   // V^T: rows e, cols l
    __shared__ __align__(16) short Kt[64 * SP];   // K'^T: rows d, cols l
    const int c = blockIdx.x, h = blockIdx.y;
    const int tid = threadIdx.x, lane = tid & 63, wave = tid >> 6;
    const int frow = lane & 15;
    const int quad = lane >> 4;
    const int fko  = quad << 3;
    const int wm   = wave << 4;
    const short* Kg = Kb + ((size_t)h * L_SEQ + (size_t)c * CHUNK) * HD;
    const short* Vg = Vb + ((size_t)h * L_SEQ + (size_t)c * CHUNK) * HD;

#pragma unroll
    for (int q = 0; q < 2; ++q) {
        const int idx = q * 256 + tid;            // 512 chunks of 8
        const int l = idx >> 3, c8 = (idx & 7) << 3;
        const bf16x8 vv = *(const bf16x8*)&Vg[l * 64 + c8];
        const bf16x8 kk = *(const bf16x8*)&Kg[l * 64 + c8];
#pragma unroll
        for (int j = 0; j < 8; ++j) {
            Vt[(c8 + j) * SP + l] = vv[j];
            Kt[(c8 + j) * SP + l] = kk[j];
        }
    }
    __syncthreads();

    const bf16x8 af0 = *(const bf16x8*)&Vt[(wm + frow) * SP + fko];
    const bf16x8 af1 = *(const bf16x8*)&Vt[(wm + frow) * SP + 32 + fko];

    floatx4 acc[4] = {};
#pragma unroll
    for (int n = 0; n < 4; ++n) {
        const bf16x8 kf0 = *(const bf16x8*)&Kt[(n * 16 + frow) * SP + fko];
        const bf16x8 kf1 = *(const bf16x8*)&Kt[(n * 16 + frow) * SP + 32 + fko];
        acc[n] = MFMA16(af0, kf0, acc[n], 0, 0, 0);
        acc[n] = MFMA16(af1, kf1, acc[n], 0, 0, 0);
    }

    short* Sout = ScTb + (size_t)(h * NCHUNK + c) * 4096;
#pragma unroll
    for (int n = 0; n < 4; ++n)
#pragma unroll
        for (int r = 0; r < 4; ++r) {
            const int e = wm + quad * 4 + r;
            const int d = n * 16 + frow;
            Sout[e * 64 + d] = f2bf(acc[n][r]);
        }

    if (wave == 0) {   // z[d] = sum_l K'[l][d] via all-ones A fragment
        bf16x8 ones;
#pragma unroll
        for (int j = 0; j < 8; ++j) ones[j] = (short)0x3F80;
        floatx4 zacc[4] = {};
#pragma unroll
        for (int n = 0; n < 4; ++n) {
            const bf16x8 kf0 = *(const bf16x8*)&Kt[(n * 16 + frow) * SP + fko];
            const bf16x8 kf1 = *(const bf16x8*)&Kt[(n * 16 + frow) * SP + 32 + fko];
            zacc[n] = MFMA16(ones, kf0, zacc[n], 0, 0, 0);
            zacc[n] = MFMA16(ones, kf1, zacc[n], 0, 0, 0);
        }
        if (quad == 0) {
#pragma unroll
            for (int n = 0; n < 4; ++n)
                zc[(size_t)(h * NCHUNK + c) * 64 + n * 16 + frow] = zacc[n][0];
        }
    }
}

// ---------------------------------------------------------------------------
// K3: exclusive prefix over chunks, 8-deep batched loads. (unchanged)
// ---------------------------------------------------------------------------
__global__ __launch_bounds__(256)
void prefix_scan(const short* __restrict__ ScTb, const float* __restrict__ zc,
                 short* __restrict__ S0b)
{
    const int g = blockIdx.x * 256 + threadIdx.x;
    const int h  = g >> 12;
    const int ed = g & 4095;
    const int e  = ed >> 6;
    const int d  = ed & 63;
    const short* src = ScTb + (size_t)h * NCHUNK * 4096 + ed;
    float run = 0.f;
    for (int cb = 0; cb < NCHUNK; cb += 8) {
        short v[8];
#pragma unroll
        for (int u = 0; u < 8; ++u) v[u] = src[(size_t)(cb + u) * 4096];
#pragma unroll
        for (int u = 0; u < 8; ++u) {
            S0b[((size_t)((h * NCHUNK + cb + u) * 65 + e)) * 64 + d] = f2bf(run);
            run += bf2f(v[u]);
        }
    }
    if (g < NH * HD) {
        const int h2 = g >> 6, d2 = g & 63;
        float rz = 0.f;
        for (int cb = 0; cb < NCHUNK; cb += 8) {
            float w[8];
#pragma unroll
            for (int u = 0; u < 8; ++u)
                w[u] = zc[((size_t)(h2 * NCHUNK + cb + u)) * HD + d2];
#pragma unroll
            for (int u = 0; u < 8; ++u) {
                S0b[((size_t)((h2 * NCHUNK + cb + u) * 65 + 64)) * 64 + d2] = f2bf(rz);
                rz += w[u];
            }
        }
    }
}

// ---------------------------------------------------------------------------
// K4: per-(head,chunk) intra-chunk attention — v2: Q,K,V ALL staged in LDS
// via coalesced bf16x8 loads (fixes 8x over-fetch of the direct per-fragment
// global reads; they were 16B-used-of-128B-line at 4 blocks/CU TLP).
// LDS 37 KB -> still 4 blocks/CU (grid caps at 4/CU anyway).
// ---------------------------------------------------------------------------
__global__ __launch_bounds__(256)
void chunk_attn(const short* __restrict__ Qb, const short* __restrict__ Kb,
                const short* __restrict__ Vb, const short* __restrict__ S0b,
                short* __restrict__ attn)
{
    __shared__ __align__(16) short Vs[65 * SP];   // V^T, row 64 = ones
    __shared__ __align__(16) short Ks[64 * SP];   // K rows (l x d)
    __shared__ __align__(16) short Qs[64 * SP];   // Q rows (l x d)
    __shared__ __align__(16) short As[64 * SP];
    const int c = blockIdx.x, h = blockIdx.y;
    const int tid = threadIdx.x, lane = tid & 63, wave = tid >> 6;
    const size_t rb = ((size_t)h * L_SEQ + (size_t)c * CHUNK) * HD;
    const short* Qg = Qb + rb;
    const short* Kg = Kb + rb;
    const short* Vg = Vb + rb;
    const short* Sg = S0b + (size_t)(h * NCHUNK + c) * 65 * 64;

#pragma unroll
    for (int q = 0; q < 2; ++q) {
        const int idx = q * 256 + tid;
        const int row = idx >> 3, c8 = (idx & 7) << 3;
        const bf16x8 vv = *(const bf16x8*)&Vg[row * 64 + c8];
        const bf16x8 kk = *(const bf16x8*)&Kg[row * 64 + c8];
        const bf16x8 qq = *(const bf16x8*)&Qg[row * 64 + c8];
#pragma unroll
        for (int j = 0; j < 8; ++j) Vs[(c8 + j) * SP + row] = vv[j];   // V^T
        *(bf16x8*)&Ks[row * SP + c8] = kk;                             // K rows
        *(bf16x8*)&Qs[row * SP + c8] = qq;                             // Q rows
    }
    if (tid < 64) Vs[64 * SP + tid] = (short)0x3F80;                   // ones
    __syncthreads();

    const int frow = lane & 15;
    const int quad = lane >> 4;
    const int fko  = quad << 3;
    const int wm   = wave << 4;

    const bf16x8 qf0 = *(const bf16x8*)&Qs[(wm + frow) * SP + fko];
    const bf16x8 qf1 = *(const bf16x8*)&Qs[(wm + frow) * SP + 32 + fko];

    floatx4 sacc[4] = {};
#pragma unroll
    for (int n = 0; n < 4; ++n) {
        const bf16x8 kf0 = *(const bf16x8*)&Ks[(n * 16 + frow) * SP + fko];
        const bf16x8 kf1 = *(const bf16x8*)&Ks[(n * 16 + frow) * SP + 32 + fko];
        sacc[n] = MFMA16(qf0, kf0, sacc[n], 0, 0, 0);
        sacc[n] = MFMA16(qf1, kf1, sacc[n], 0, 0, 0);
    }
#pragma unroll
    for (int n = 0; n < 4; ++n)
#pragma unroll
        for (int r = 0; r < 4; ++r) {
            const int i = wm + quad * 4 + r;
            const int j = n * 16 + frow;
            As[i * SP + j] = (j <= i) ? f2bf(sacc[n][r]) : (short)0;
        }
    const bf16x8 af0 = *(const bf16x8*)&As[(wm + frow) * SP + fko];
    const bf16x8 af1 = *(const bf16x8*)&As[(wm + frow) * SP + 32 + fko];

    floatx4 oacc[5] = {};
#pragma unroll
    for (int n = 0; n < 4; ++n) {
        const bf16x8 vf0 = *(const bf16x8*)&Vs[(n * 16 + frow) * SP + fko];
        const bf16x8 vf1 = *(const bf16x8*)&Vs[(n * 16 + frow) * SP + 32 + fko];
        oacc[n] = MFMA16(af0, vf0, oacc[n], 0, 0, 0);
        oacc[n] = MFMA16(af1, vf1, oacc[n], 0, 0, 0);
        const bf16x8 sf0 = *(const bf16x8*)&Sg[(n * 16 + frow) * 64 + fko];
        const bf16x8 sf1 = *(const bf16x8*)&Sg[(n * 16 + frow) * 64 + 32 + fko];
        oacc[n] = MFMA16(qf0, sf0, oacc[n], 0, 0, 0);
        oacc[n] = MFMA16(qf1, sf1, oacc[n], 0, 0, 0);
    }
    {   // tile 4: broadcast row 64 (ones / z0) -> col 64 = norm
        const bf16x8 vf0 = *(const bf16x8*)&Vs[64 * SP + fko];
        const bf16x8 vf1 = *(const bf16x8*)&Vs[64 * SP + 32 + fko];
        oacc[4] = MFMA16(af0, vf0, oacc[4], 0, 0, 0);
        oacc[4] = MFMA16(af1, vf1, oacc[4], 0, 0, 0);
        const bf16x8 sf0 = *(const bf16x8*)&Sg[64 * 64 + fko];
        const bf16x8 sf1 = *(const bf16x8*)&Sg[64 * 64 + 32 + fko];
        oacc[4] = MFMA16(qf0, sf0, oacc[4], 0, 0, 0);
        oacc[4] = MFMA16(qf1, sf1, oacc[4], 0, 0, 0);
    }
#pragma unroll
    for (int r = 0; r < 4; ++r) {
        const float norm = __shfl(oacc[4][r], lane & 48) + EPS;
        const float inv = 1.f / norm;
        const int i = wm + quad * 4 + r;
#pragma unroll
        for (int n = 0; n < 4; ++n)
            As[i * SP + n * 16 + frow] = f2bf(oacc[n][r] * inv);
    }
    __syncthreads();
#pragma unroll
    for (int t = 0; t < 2; ++t) {
        const int idx = t * 256 + tid;
        const int row = idx >> 3, c8 = (idx & 7) << 3;
        *(bf16x8*)&attn[(size_t)(c * CHUNK + row) * EMB + h * HD + c8] =
            *(const bf16x8*)&As[row * SP + c8];
    }
}

// ---------------------------------------------------------------------------
extern "C" void kernel_launch(void* const* d_in, const int* in_sizes, int n_in,
                              void* d_out, int out_size, void* d_ws, size_t ws_size,
                              hipStream_t stream)
{
    const float* x     = (const float*)d_in[0];
    const float* qkv_w = (const float*)d_in[1];
    const float* qkv_b = (const float*)d_in[2];
    const float* out_w = (const float*)d_in[3];
    const float* out_b = (const float*)d_in[4];
    float* out = (float*)d_out;

    short* ws    = (short*)d_ws;
    short* Qb    = ws;                   // head-major bf16, 4194304 each
    short* Kb    = Qb + 4194304;
    short* Vb    = Kb + 4194304;
    short* xb    = Vb + 4194304;
    short* qwt   = xb + 4194304;         // 3072 x 1024
    short* owt   = qwt + 3145728;        // 1024 x 1024
    short* attnb = owt + 1048576;        // 4096 x 1024
    short* ScTb  = attnb + 4194304;      // 1024 * 64 * 64
    short* S0b   = ScTb + 4194304;       // 1024 * 65 * 64
    float* zc    = (float*)(S0b + 4259840);    // 65536 fp32

    prep<<<dim3(3072), 256, 0, stream>>>(x, xb, qkv_w, qwt, out_w, owt);
    mfma_gemm_qkv256<<<dim3(N3 / 256, L_SEQ / 256), 512, 0, stream>>>(
        xb, qwt, qkv_b, Qb, Kb, Vb);
    chunk_state<<<dim3(NCHUNK, NH), 256, 0, stream>>>(Kb, Vb, ScTb, zc);
    prefix_scan<<<dim3((NH * 4096) / 256), 256, 0, stream>>>(ScTb, zc, S0b);
    chunk_attn<<<dim3(NCHUNK, NH), 256, 0, stream>>>(Qb, Kb, Vb, S0b, attnb);
    mfma_gemm_out<<<dim3(EMB / 128, L_SEQ / 64), 256, 0, stream>>>(
        attnb, owt, out_b, out, EMB, EMB);
}

// Round 6
// 158.927 us; speedup vs baseline: 2.7052x; 1.0397x over previous
//
#include <hip/hip_runtime.h>
#include <cstddef>
#include <cstdint>

#define L_SEQ 4096
#define EMB   1024
#define NH    16
#define HD    64
#define N3    3072
#define CHUNK 64
#define NCHUNK 64
#define EPS 1e-6f

typedef __attribute__((ext_vector_type(8))) short   bf16x8;
typedef __attribute__((ext_vector_type(4))) short   bf16x4;
typedef __attribute__((ext_vector_type(4))) float   floatx4;

#define AS1 __attribute__((address_space(1)))
#define AS3 __attribute__((address_space(3)))

__device__ __forceinline__ void gload_lds16(const void* g, void* l) {
    __builtin_amdgcn_global_load_lds((AS1 const unsigned int*)g,
                                     (AS3 unsigned int*)l, 16, 0, 0);
}

// round-to-nearest-even fp32 -> bf16 bits
__device__ __forceinline__ short f2bf(float f) {
    union { float f; unsigned u; } a; a.f = f;
    unsigned r = a.u + 0x7fffu + ((a.u >> 16) & 1u);
    return (short)(r >> 16);
}
__device__ __forceinline__ float bf2f(short s) {
    union { unsigned u; float f; } a; a.u = ((unsigned)(unsigned short)s) << 16;
    return a.f;
}

// ---------------------------------------------------------------------------
// K0: fused prep — blocks [0,2048): x->bf16; [2048,2816): qkv_w^T;
// [2816,3072): out_w^T.
// ---------------------------------------------------------------------------
__device__ __forceinline__ void transpose_tile(const float* __restrict__ W,
                                               short* __restrict__ WT,
                                               int K, int N, int bx, int by,
                                               float (*t)[65], int tid)
{
    const int r  = tid >> 4;
    const int c4 = (tid & 15) << 2;
#pragma unroll
    for (int s = 0; s < 4; ++s) {
        const int k = r + s * 16;
        const floatx4 v = *(const floatx4*)&W[(size_t)(by * 64 + k) * N + bx * 64 + c4];
        t[k][c4 + 0] = v[0]; t[k][c4 + 1] = v[1];
        t[k][c4 + 2] = v[2]; t[k][c4 + 3] = v[3];
    }
    __syncthreads();
#pragma unroll
    for (int s = 0; s < 4; ++s) {
        const int n = r + s * 16;
        bf16x4 o;
        o[0] = f2bf(t[c4 + 0][n]); o[1] = f2bf(t[c4 + 1][n]);
        o[2] = f2bf(t[c4 + 2][n]); o[3] = f2bf(t[c4 + 3][n]);
        *(bf16x4*)&WT[(size_t)(bx * 64 + n) * K + by * 64 + c4] = o;
    }
}

__global__ __launch_bounds__(256)
void prep(const float* __restrict__ x, short* __restrict__ xb,
          const float* __restrict__ qkv_w, short* __restrict__ qwt,
          const float* __restrict__ out_w, short* __restrict__ owt)
{
    __shared__ float t[64][65];
    const int b = blockIdx.x;
    const int tid = threadIdx.x;
    if (b < 2048) {
        const int i = b * 256 + tid;
        const floatx4 a = *(const floatx4*)(x + (size_t)i * 8);
        const floatx4 c = *(const floatx4*)(x + (size_t)i * 8 + 4);
        bf16x8 o;
        o[0] = f2bf(a[0]); o[1] = f2bf(a[1]); o[2] = f2bf(a[2]); o[3] = f2bf(a[3]);
        o[4] = f2bf(c[0]); o[5] = f2bf(c[1]); o[6] = f2bf(c[2]); o[7] = f2bf(c[3]);
        *(bf16x8*)(xb + (size_t)i * 8) = o;
    } else if (b < 2048 + 768) {
        const int u = b - 2048;
        transpose_tile(qkv_w, qwt, EMB, N3, u % 48, u / 48, t, tid);
    } else {
        const int u = b - 2816;
        transpose_tile(out_w, owt, EMB, EMB, u & 15, u >> 4, t, tid);
    }
}

// ---------------------------------------------------------------------------
// K1: qkv GEMM — v3: 256x192 tile, grid 16x16 = 256 blocks (1/CU, 100% CU
// coverage; the 256x256 grid had 192 blocks = 75%). BK=64, 8 waves (2Mx4N,
// per-wave 128x48, 12 MFMA/phase), 8-phase schedule.
// 3-bit XOR swizzle (row bits 1-3 -> col 16B-slot bits): within a 16-lane
// LDS service group all 8 column slots are hit (2 lanes/slot = free) —
// the old 2-bit swizzle left 4-way conflicts (2.75M conflict cycles, R5).
// LDS (shorts): buf0.A=0(16K) buf0.B=16384(12K) buf1.A=28672 buf1.B=45056.
// Loads/K-tile: A=4, B=3. vmcnt(3) at ph4/ph8:
//   ph1:+4(buf1.A t1) ph2:+3(buf0.B t0+2) ph4:vmcnt(3) completes buf1
//   ph5:+2 ph6:+2 (buf0.A t0+2) ph7:+3(buf1.B t1+2) ph8:vmcnt(3) completes buf0
// ---------------------------------------------------------------------------
#define MFMA16 __builtin_amdgcn_mfma_f32_16x16x32_bf16

__global__ __launch_bounds__(512, 2)
void mfma_gemm_qkv256(const short* __restrict__ A, const short* __restrict__ BT,
                      const float* __restrict__ bias,
                      short* __restrict__ OQ, short* __restrict__ OK,
                      short* __restrict__ OV)
{
    __shared__ __align__(16) short lds[57344];   // 112 KiB
    const int tid  = threadIdx.x;
    const int lane = tid & 63;
    const int wave = tid >> 6;           // 0..7
    const int wr   = wave >> 2;          // 0..1 (M half)
    const int wc   = wave & 3;           // 0..3 (N quarter, 48 cols each)
    const int frow = lane & 15;
    const int quad = lane >> 4;
    const int q8   = quad * 8;
    const int bx = blockIdx.x;           // N tiles: 16 (192 each)
    const int by = blockIdx.y;           // M tiles: 16 (256 each)

    const short* Ab = A  + (size_t)(by * 256) * 1024;
    const short* Bb = BT + (size_t)(bx * 192) * 1024;

    // staging constants (linear LDS dst, inverse-swizzled global src)
    const int trow = tid >> 3;                       // 0..63
    const int ccol = (tid & 7) * 8;                  // dst col chunk, shorts
    const int scol = ccol ^ ((trow & 14) << 2);      // 3-bit swizzled src col
    const int sx   = (frow & 14) << 2;               // read-side XOR, shorts
    const int wcb  = wc * 48 + frow;                 // B fragment row base

// A-half stage: 128 rows (2 x 64), rows j*64+trow, GPTR at half base
#define STG_A(LBASE, GPTR) do {                                             \
        const short* g_ = (GPTR);                                           \
        _Pragma("unroll")                                                   \
        for (int j_ = 0; j_ < 2; ++j_) {                                    \
            const int r_ = j_ * 64 + trow;                                  \
            gload_lds16(g_ + (size_t)r_ * 1024 + scol,                      \
                        &lds[(LBASE) + r_ * 64 + ccol]);                    \
        }                                                                   \
    } while (0)

// B stage: 192 rows (3 x 64)
#define STG_B(LBASE, GPTR) do {                                             \
        const short* g_ = (GPTR);                                           \
        _Pragma("unroll")                                                   \
        for (int j_ = 0; j_ < 3; ++j_) {                                    \
            const int r_ = j_ * 64 + trow;                                  \
            gload_lds16(g_ + (size_t)r_ * 1024 + scol,                      \
                        &lds[(LBASE) + r_ * 64 + ccol]);                    \
        }                                                                   \
    } while (0)

#define LDA(BASE, R, KS) \
    (*(const bf16x8*)&lds[(BASE) + (R) * 64 + ((((KS) * 32) + q8) ^ sx)])

    floatx4 acc[8][3] = {};
    bf16x8  bq[3][2];

#define PHASE(ABASE, BBASE, QD, RDB, VM, ...) do {                          \
        const int Rr_ = wr * 128 + (QD) * 32 + frow;                        \
        bf16x8 a0_ = LDA((ABASE), Rr_,      0);                             \
        bf16x8 a1_ = LDA((ABASE), Rr_,      1);                             \
        bf16x8 a2_ = LDA((ABASE), Rr_ + 16, 0);                             \
        bf16x8 a3_ = LDA((ABASE), Rr_ + 16, 1);                             \
        if (RDB) {                                                          \
            _Pragma("unroll")                                               \
            for (int ni_ = 0; ni_ < 3; ++ni_) {                             \
                bq[ni_][0] = LDA((BBASE), wcb + ni_ * 16, 0);               \
                bq[ni_][1] = LDA((BBASE), wcb + ni_ * 16, 1);               \
            }                                                               \
        }                                                                   \
        __VA_ARGS__;                                                        \
        __builtin_amdgcn_sched_barrier(0);                                  \
        __builtin_amdgcn_s_barrier();                                       \
        asm volatile("s_waitcnt lgkmcnt(0)" ::: "memory");                  \
        __builtin_amdgcn_sched_barrier(0);                                  \
        __builtin_amdgcn_s_setprio(1);                                      \
        _Pragma("unroll")                                                   \
        for (int ni_ = 0; ni_ < 3; ++ni_) {                                 \
            acc[2*(QD)  ][ni_] = MFMA16(a0_, bq[ni_][0], acc[2*(QD)  ][ni_], 0,0,0); \
            acc[2*(QD)  ][ni_] = MFMA16(a1_, bq[ni_][1], acc[2*(QD)  ][ni_], 0,0,0); \
            acc[2*(QD)+1][ni_] = MFMA16(a2_, bq[ni_][0], acc[2*(QD)+1][ni_], 0,0,0); \
            acc[2*(QD)+1][ni_] = MFMA16(a3_, bq[ni_][1], acc[2*(QD)+1][ni_], 0,0,0); \
        }                                                                   \
        __builtin_amdgcn_s_setprio(0);                                      \
        if (VM) asm volatile("s_waitcnt vmcnt(3)" ::: "memory");            \
        __builtin_amdgcn_s_barrier();                                       \
        __builtin_amdgcn_sched_barrier(0);                                  \
    } while (0)

    // prologue: tile0 A+B -> buf0, tile1 B -> buf1 (10 loads), drain to 3
    STG_A(0,     Ab);                    // buf0.A h0
    STG_A(8192,  Ab + 131072);           // buf0.A h1
    STG_B(16384, Bb);                    // buf0.B
    STG_B(45056, Bb + 64);               // buf1.B (tile1)
    asm volatile("s_waitcnt vmcnt(3)" ::: "memory");
    __builtin_amdgcn_s_barrier();
    __builtin_amdgcn_sched_barrier(0);

#pragma unroll 1
    for (int it = 0; it < 8; ++it) {
        const int k1  = (2 * it + 1) * 64;             // odd tile k-offset
        const int kn0 = ((2 * it + 2) & 15) * 64;      // next even (wrapped)
        const int kn1 = ((2 * it + 3) & 15) * 64;      // next odd (wrapped)

        // even tile from buf0
        PHASE(0, 16384, 0, 1, 0,
              STG_A(28672, Ab + k1); STG_A(36864, Ab + 131072 + k1));
        PHASE(0, 16384, 1, 0, 0, STG_B(16384, Bb + kn0));
        PHASE(0, 16384, 2, 0, 0, ((void)0));
        PHASE(0, 16384, 3, 0, 1, ((void)0));
        // odd tile from buf1
        PHASE(28672, 45056, 0, 1, 0, STG_A(0, Ab + kn0));
        PHASE(28672, 45056, 1, 0, 0, STG_A(8192, Ab + 131072 + kn0));
        PHASE(28672, 45056, 2, 0, 0, STG_B(45056, Bb + kn1));
        PHASE(28672, 45056, 3, 0, 1, ((void)0));
    }

    __syncthreads();   // full drain (incl. wrapped tail stages); LDS reuse safe

    // epilogue: per-wave 128x48 repack -> bias + elu(q,k) -> head-major scatter
    const int wbase = wave * 6144;
    const int colg0 = bx * 192 + wc * 48;
    const int L0 = by * 256 + wr * 128;
#pragma unroll
    for (int ni = 0; ni < 3; ++ni) {
        const int n = colg0 + ni * 16 + frow;
        const float bv = bias[n];
        const bool do_elu = (n >> 10) < 2;
#pragma unroll
        for (int mi = 0; mi < 8; ++mi)
#pragma unroll
            for (int r = 0; r < 4; ++r) {
                float v = acc[mi][ni][r] + bv;
                if (do_elu) v = (v > 0.f) ? (v + 1.f) : __expf(v);
                lds[wbase + (mi * 16 + quad * 4 + r) * 48 + ni * 16 + frow] = f2bf(v);
            }
    }
    // within-wave write->read; compiler inserts lgkm waits
#pragma unroll
    for (int s = 0; s < 12; ++s) {
        const int chunk = s * 64 + lane;     // 768 chunks of 8 shorts
        const int row = chunk / 6, cc = (chunk % 6) * 8;
        const bf16x8 val = *(const bf16x8*)&lds[wbase + row * 48 + cc];
        const int n0 = colg0 + cc;
        const int rsel = n0 >> 10;
        const int h = (n0 & 1023) >> 6;
        const int d = n0 & 63;
        short* base = (rsel == 0) ? OQ : (rsel == 1 ? OK : OV);
        *(bf16x8*)&base[((size_t)(h * L_SEQ + L0 + row)) * HD + d] = val;
    }
#undef PHASE
#undef LDA
#undef STG_A
#undef STG_B
}

// ---------------------------------------------------------------------------
// K5: out-projection GEMM, 64x128 tile (512 blocks = 2/CU), double-panel.
// ---------------------------------------------------------------------------
__global__ __launch_bounds__(256)
void mfma_gemm_out(const short* __restrict__ A, const short* __restrict__ BT,
                   const float* __restrict__ bias, float* __restrict__ OF,
                   int N, int K)
{
    __shared__ __align__(16) short smem[12288];
    short* pan[4] = { smem, smem + 2048, smem + 6144, smem + 8192 };
    const int tid  = threadIdx.x;
    const int lane = tid & 63;
    const int wave = tid >> 6;
    const int wm = (wave >> 1) * 32;
    const int wn = (wave & 1) * 64;
    const int bx = blockIdx.x;
    const int by = blockIdx.y;
    const int frow = lane & 15;
    const int quad = lane >> 4;
    const int fko  = quad << 3;

    const short* Ab = A  + (size_t)(by * 64) * K;
    const short* Bb = BT + (size_t)(bx * 128) * K;

    floatx4 acc[2][4] = {};

    for (int k0 = 0; k0 < K; k0 += 64) {
#pragma unroll
        for (int p = 0; p < 2; ++p) {
            const int kp = k0 + p * 32;
            {
                const int row = tid >> 2;
                const int kc  = (tid & 3) << 3;
                gload_lds16(Ab + (size_t)row * K + kp + kc, &pan[p * 2 + 0][tid << 3]);
            }
#pragma unroll
            for (int q = 0; q < 2; ++q) {
                const int ib = q * 256 + tid;
                const int row = ib >> 2;
                const int kc  = (ib & 3) << 3;
                gload_lds16(Bb + (size_t)row * K + kp + kc, &pan[p * 2 + 1][ib << 3]);
            }
        }
        __syncthreads();
#pragma unroll
        for (int p = 0; p < 2; ++p) {
            bf16x8 af[2], bfv[4];
#pragma unroll
            for (int mi = 0; mi < 2; ++mi)
                af[mi] = *(const bf16x8*)&pan[p * 2 + 0][(wm + mi * 16 + frow) * 32 + fko];
#pragma unroll
            for (int ni = 0; ni < 4; ++ni)
                bfv[ni] = *(const bf16x8*)&pan[p * 2 + 1][(wn + ni * 16 + frow) * 32 + fko];
#pragma unroll
            for (int mi = 0; mi < 2; ++mi)
#pragma unroll
                for (int ni = 0; ni < 4; ++ni)
                    acc[mi][ni] = __builtin_amdgcn_mfma_f32_16x16x32_bf16(
                        af[mi], bfv[ni], acc[mi][ni], 0, 0, 0);
        }
        __syncthreads();
    }

    const int rq = quad << 2;
#pragma unroll
    for (int ni = 0; ni < 4; ++ni) {
        const int n = bx * 128 + wn + ni * 16 + frow;
        const float bv = bias[n];
#pragma unroll
        for (int mi = 0; mi < 2; ++mi)
#pragma unroll
            for (int r = 0; r < 4; ++r) {
                const int m = by * 64 + wm + mi * 16 + rq + r;
                OF[(size_t)m * N + n] = acc[mi][ni][r] + bv;
            }
    }
}

// ---------------------------------------------------------------------------
// K2: per-(head,chunk) state sums, MFMA version. (unchanged)
// ---------------------------------------------------------------------------
#define SP 72

__global__ __launch_bounds__(256, 4)
void chunk_state(const short* __restrict__ Kb, const short* __restrict__ Vb,
                 short* __restrict__ ScTb, float* __restrict__ zc)
{
    __shared__ __align__(16) short Vt[64 * SP];   // V^T: rows e, cols l
    __shared__ __align__(16) short Kt[64 * SP];   // K'^T: rows d, cols l
    const int c = blockIdx.x, h = blockIdx.y;
    const int tid = threadIdx.x, lane = tid & 63, wave = tid >> 6;
    const int frow = lane & 15;
    const int quad = lane >> 4;
    const int fko  = quad << 3;
    const int wm   = wave << 4;
    const short* Kg = Kb + ((size_t)h * L_SEQ + (size_t)c * CHUNK) * HD;
    const short* Vg = Vb + ((size_t)h * L_SEQ + (size_t)c * CHUNK) * HD;

#pragma unroll
    for (int q = 0; q < 2; ++q) {
        const int idx = q * 256 + tid;            // 512 chunks of 8
        const int l = idx >> 3, c8 = (idx & 7) << 3;
        const bf16x8 vv = *(const bf16x8*)&Vg[l * 64 + c8];
        const bf16x8 kk = *(const bf16x8*)&Kg[l * 64 + c8];
#pragma unroll
        for (int j = 0; j < 8; ++j) {
            Vt[(c8 + j) * SP + l] = vv[j];
            Kt[(c8 + j) * SP + l] = kk[j];
        }
    }
    __syncthreads();

    const bf16x8 af0 = *(const bf16x8*)&Vt[(wm + frow) * SP + fko];
    const bf16x8 af1 = *(const bf16x8*)&Vt[(wm + frow) * SP + 32 + fko];

    floatx4 acc[4] = {};
#pragma unroll
    for (int n = 0; n < 4; ++n) {
        const bf16x8 kf0 = *(const bf16x8*)&Kt[(n * 16 + frow) * SP + fko];
        const bf16x8 kf1 = *(const bf16x8*)&Kt[(n * 16 + frow) * SP + 32 + fko];
        acc[n] = MFMA16(af0, kf0, acc[n], 0, 0, 0);
        acc[n] = MFMA16(af1, kf1, acc[n], 0, 0, 0);
    }

    short* Sout = ScTb + (size_t)(h * NCHUNK + c) * 4096;
#pragma unroll
    for (int n = 0; n < 4; ++n)
#pragma unroll
        for (int r = 0; r < 4; ++r) {
            const int e = wm + quad * 4 + r;
            const int d = n * 16 + frow;
            Sout[e * 64 + d] = f2bf(acc[n][r]);
        }

    if (wave == 0) {   // z[d] = sum_l K'[l][d] via all-ones A fragment
        bf16x8 ones;
#pragma unroll
        for (int j = 0; j < 8; ++j) ones[j] = (short)0x3F80;
        floatx4 zacc[4] = {};
#pragma unroll
        for (int n = 0; n < 4; ++n) {
            const bf16x8 kf0 = *(const bf16x8*)&Kt[(n * 16 + frow) * SP + fko];
            const bf16x8 kf1 = *(const bf16x8*)&Kt[(n * 16 + frow) * SP + 32 + fko];
            zacc[n] = MFMA16(ones, kf0, zacc[n], 0, 0, 0);
            zacc[n] = MFMA16(ones, kf1, zacc[n], 0, 0, 0);
        }
        if (quad == 0) {
#pragma unroll
            for (int n = 0; n < 4; ++n)
                zc[(size_t)(h * NCHUNK + c) * 64 + n * 16 + frow] = zacc[n][0];
        }
    }
}

// ---------------------------------------------------------------------------
// K3: exclusive prefix over chunks, 8-deep batched loads. (unchanged)
// ---------------------------------------------------------------------------
__global__ __launch_bounds__(256)
void prefix_scan(const short* __restrict__ ScTb, const float* __restrict__ zc,
                 short* __restrict__ S0b)
{
    const int g = blockIdx.x * 256 + threadIdx.x;
    const int h  = g >> 12;
    const int ed = g & 4095;
    const int e  = ed >> 6;
    const int d  = ed & 63;
    const short* src = ScTb + (size_t)h * NCHUNK * 4096 + ed;
    float run = 0.f;
    for (int cb = 0; cb < NCHUNK; cb += 8) {
        short v[8];
#pragma unroll
        for (int u = 0; u < 8; ++u) v[u] = src[(size_t)(cb + u) * 4096];
#pragma unroll
        for (int u = 0; u < 8; ++u) {
            S0b[((size_t)((h * NCHUNK + cb + u) * 65 + e)) * 64 + d] = f2bf(run);
            run += bf2f(v[u]);
        }
    }
    if (g < NH * HD) {
        const int h2 = g >> 6, d2 = g & 63;
        float rz = 0.f;
        for (int cb = 0; cb < NCHUNK; cb += 8) {
            float w[8];
#pragma unroll
            for (int u = 0; u < 8; ++u)
                w[u] = zc[((size_t)(h2 * NCHUNK + cb + u)) * HD + d2];
#pragma unroll
            for (int u = 0; u < 8; ++u) {
                S0b[((size_t)((h2 * NCHUNK + cb + u) * 65 + 64)) * 64 + d2] = f2bf(rz);
                rz += w[u];
            }
        }
    }
}

// ---------------------------------------------------------------------------
// K4: per-(head,chunk) intra-chunk attention — Q,K,V staged in LDS (R5, passed)
// ---------------------------------------------------------------------------
__global__ __launch_bounds__(256)
void chunk_attn(const short* __restrict__ Qb, const short* __restrict__ Kb,
                const short* __restrict__ Vb, const short* __restrict__ S0b,
                short* __restrict__ attn)
{
    __shared__ __align__(16) short Vs[65 * SP];   // V^T, row 64 = ones
    __shared__ __align__(16) short Ks[64 * SP];   // K rows (l x d)
    __shared__ __align__(16) short Qs[64 * SP];   // Q rows (l x d)
    __shared__ __align__(16) short As[64 * SP];
    const int c = blockIdx.x, h = blockIdx.y;
    const int tid = threadIdx.x, lane = tid & 63, wave = tid >> 6;
    const size_t rb = ((size_t)h * L_SEQ + (size_t)c * CHUNK) * HD;
    const short* Qg = Qb + rb;
    const short* Kg = Kb + rb;
    const short* Vg = Vb + rb;
    const short* Sg = S0b + (size_t)(h * NCHUNK + c) * 65 * 64;

#pragma unroll
    for (int q = 0; q < 2; ++q) {
        const int idx = q * 256 + tid;
        const int row = idx >> 3, c8 = (idx & 7) << 3;
        const bf16x8 vv = *(const bf16x8*)&Vg[row * 64 + c8];
        const bf16x8 kk = *(const bf16x8*)&Kg[row * 64 + c8];
        const bf16x8 qq = *(const bf16x8*)&Qg[row * 64 + c8];
#pragma unroll
        for (int j = 0; j < 8; ++j) Vs[(c8 + j) * SP + row] = vv[j];   // V^T
        *(bf16x8*)&Ks[row * SP + c8] = kk;                             // K rows
        *(bf16x8*)&Qs[row * SP + c8] = qq;                             // Q rows
    }
    if (tid < 64) Vs[64 * SP + tid] = (short)0x3F80;                   // ones
    __syncthreads();

    const int frow = lane & 15;
    const int quad = lane >> 4;
    const int fko  = quad << 3;
    const int wm   = wave << 4;

    const bf16x8 qf0 = *(const bf16x8*)&Qs[(wm + frow) * SP + fko];
    const bf16x8 qf1 = *(const bf16x8*)&Qs[(wm + frow) * SP + 32 + fko];

    floatx4 sacc[4] = {};
#pragma unroll
    for (int n = 0; n < 4; ++n) {
        const bf16x8 kf0 = *(const bf16x8*)&Ks[(n * 16 + frow) * SP + fko];
        const bf16x8 kf1 = *(const bf16x8*)&Ks[(n * 16 + frow) * SP + 32 + fko];
        sacc[n] = MFMA16(qf0, kf0, sacc[n], 0, 0, 0);
        sacc[n] = MFMA16(qf1, kf1, sacc[n], 0, 0, 0);
    }
#pragma unroll
    for (int n = 0; n < 4; ++n)
#pragma unroll
        for (int r = 0; r < 4; ++r) {
            const int i = wm + quad * 4 + r;
            const int j = n * 16 + frow;
            As[i * SP + j] = (j <= i) ? f2bf(sacc[n][r]) : (short)0;
        }
    const bf16x8 af0 = *(const bf16x8*)&As[(wm + frow) * SP + fko];
    const bf16x8 af1 = *(const bf16x8*)&As[(wm + frow) * SP + 32 + fko];

    floatx4 oacc[5] = {};
#pragma unroll
    for (int n = 0; n < 4; ++n) {
        const bf16x8 vf0 = *(const bf16x8*)&Vs[(n * 16 + frow) * SP + fko];
        const bf16x8 vf1 = *(const bf16x8*)&Vs[(n * 16 + frow) * SP + 32 + fko];
        oacc[n] = MFMA16(af0, vf0, oacc[n], 0, 0, 0);
        oacc[n] = MFMA16(af1, vf1, oacc[n], 0, 0, 0);
        const bf16x8 sf0 = *(const bf16x8*)&Sg[(n * 16 + frow) * 64 + fko];
        const bf16x8 sf1 = *(const bf16x8*)&Sg[(n * 16 + frow) * 64 + 32 + fko];
        oacc[n] = MFMA16(qf0, sf0, oacc[n], 0, 0, 0);
        oacc[n] = MFMA16(qf1, sf1, oacc[n], 0, 0, 0);
    }
    {   // tile 4: broadcast row 64 (ones / z0) -> col 64 = norm
        const bf16x8 vf0 = *(const bf16x8*)&Vs[64 * SP + fko];
        const bf16x8 vf1 = *(const bf16x8*)&Vs[64 * SP + 32 + fko];
        oacc[4] = MFMA16(af0, vf0, oacc[4], 0, 0, 0);
        oacc[4] = MFMA16(af1, vf1, oacc[4], 0, 0, 0);
        const bf16x8 sf0 = *(const bf16x8*)&Sg[64 * 64 + fko];
        const bf16x8 sf1 = *(const bf16x8*)&Sg[64 * 64 + 32 + fko];
        oacc[4] = MFMA16(qf0, sf0, oacc[4], 0, 0, 0);
        oacc[4] = MFMA16(qf1, sf1, oacc[4], 0, 0, 0);
    }
#pragma unroll
    for (int r = 0; r < 4; ++r) {
        const float norm = __shfl(oacc[4][r], lane & 48) + EPS;
        const float inv = 1.f / norm;
        const int i = wm + quad * 4 + r;
#pragma unroll
        for (int n = 0; n < 4; ++n)
            As[i * SP + n * 16 + frow] = f2bf(oacc[n][r] * inv);
    }
    __syncthreads();
#pragma unroll
    for (int t = 0; t < 2; ++t) {
        const int idx = t * 256 + tid;
        const int row = idx >> 3, c8 = (idx & 7) << 3;
        *(bf16x8*)&attn[(size_t)(c * CHUNK + row) * EMB + h * HD + c8] =
            *(const bf16x8*)&As[row * SP + c8];
    }
}

// ---------------------------------------------------------------------------
extern "C" void kernel_launch(void* const* d_in, const int* in_sizes, int n_in,
                              void* d_out, int out_size, void* d_ws, size_t ws_size,
                              hipStream_t stream)
{
    const float* x     = (const float*)d_in[0];
    const float* qkv_w = (const float*)d_in[1];
    const float* qkv_b = (const float*)d_in[2];
    const float* out_w = (const float*)d_in[3];
    const float* out_b = (const float*)d_in[4];
    float* out = (float*)d_out;

    short* ws    = (short*)d_ws;
    short* Qb    = ws;                   // head-major bf16, 4194304 each
    short* Kb    = Qb + 4194304;
    short* Vb    = Kb + 4194304;
    short* xb    = Vb + 4194304;
    short* qwt   = xb + 4194304;         // 3072 x 1024
    short* owt   = qwt + 3145728;        // 1024 x 1024
    short* attnb = owt + 1048576;        // 4096 x 1024
    short* ScTb  = attnb + 4194304;      // 1024 * 64 * 64
    short* S0b   = ScTb + 4194304;       // 1024 * 65 * 64
    float* zc    = (float*)(S0b + 4259840);    // 65536 fp32

    prep<<<dim3(3072), 256, 0, stream>>>(x, xb, qkv_w, qwt, out_w, owt);
    mfma_gemm_qkv256<<<dim3(N3 / 192, L_SEQ / 256), 512, 0, stream>>>(
        xb, qwt, qkv_b, Qb, Kb, Vb);
    chunk_state<<<dim3(NCHUNK, NH), 256, 0, stream>>>(Kb, Vb, ScTb, zc);
    prefix_scan<<<dim3((NH * 4096) / 256), 256, 0, stream>>>(ScTb, zc, S0b);
    chunk_attn<<<dim3(NCHUNK, NH), 256, 0, stream>>>(Qb, Kb, Vb, S0b, attnb);
    mfma_gemm_out<<<dim3(EMB / 128, L_SEQ / 64), 256, 0, stream>>>(
        attnb, owt, out_b, out, EMB, EMB);
}

// Round 7
// 156.278 us; speedup vs baseline: 2.7510x; 1.0169x over previous
//
#include <hip/hip_runtime.h>
#include <cstddef>
#include <cstdint>

#define L_SEQ 4096
#define EMB   1024
#define NH    16
#define HD    64
#define N3    3072
#define CHUNK 64
#define NCHUNK 64
#define EPS 1e-6f

typedef __attribute__((ext_vector_type(8))) short   bf16x8;
typedef __attribute__((ext_vector_type(4))) short   bf16x4;
typedef __attribute__((ext_vector_type(4))) float   floatx4;

#define AS1 __attribute__((address_space(1)))
#define AS3 __attribute__((address_space(3)))

__device__ __forceinline__ void gload_lds16(const void* g, void* l) {
    __builtin_amdgcn_global_load_lds((AS1 const unsigned int*)g,
                                     (AS3 unsigned int*)l, 16, 0, 0);
}

// round-to-nearest-even fp32 -> bf16 bits
__device__ __forceinline__ short f2bf(float f) {
    union { float f; unsigned u; } a; a.f = f;
    unsigned r = a.u + 0x7fffu + ((a.u >> 16) & 1u);
    return (short)(r >> 16);
}
__device__ __forceinline__ float bf2f(short s) {
    union { unsigned u; float f; } a; a.u = ((unsigned)(unsigned short)s) << 16;
    return a.f;
}

// ---------------------------------------------------------------------------
// K0: fused prep — blocks [0,2048): x->bf16; [2048,2816): qkv_w^T;
// [2816,3072): out_w^T.
// ---------------------------------------------------------------------------
__device__ __forceinline__ void transpose_tile(const float* __restrict__ W,
                                               short* __restrict__ WT,
                                               int K, int N, int bx, int by,
                                               float (*t)[65], int tid)
{
    const int r  = tid >> 4;
    const int c4 = (tid & 15) << 2;
#pragma unroll
    for (int s = 0; s < 4; ++s) {
        const int k = r + s * 16;
        const floatx4 v = *(const floatx4*)&W[(size_t)(by * 64 + k) * N + bx * 64 + c4];
        t[k][c4 + 0] = v[0]; t[k][c4 + 1] = v[1];
        t[k][c4 + 2] = v[2]; t[k][c4 + 3] = v[3];
    }
    __syncthreads();
#pragma unroll
    for (int s = 0; s < 4; ++s) {
        const int n = r + s * 16;
        bf16x4 o;
        o[0] = f2bf(t[c4 + 0][n]); o[1] = f2bf(t[c4 + 1][n]);
        o[2] = f2bf(t[c4 + 2][n]); o[3] = f2bf(t[c4 + 3][n]);
        *(bf16x4*)&WT[(size_t)(bx * 64 + n) * K + by * 64 + c4] = o;
    }
}

__global__ __launch_bounds__(256)
void prep(const float* __restrict__ x, short* __restrict__ xb,
          const float* __restrict__ qkv_w, short* __restrict__ qwt,
          const float* __restrict__ out_w, short* __restrict__ owt)
{
    __shared__ float t[64][65];
    const int b = blockIdx.x;
    const int tid = threadIdx.x;
    if (b < 2048) {
        const int i = b * 256 + tid;
        const floatx4 a = *(const floatx4*)(x + (size_t)i * 8);
        const floatx4 c = *(const floatx4*)(x + (size_t)i * 8 + 4);
        bf16x8 o;
        o[0] = f2bf(a[0]); o[1] = f2bf(a[1]); o[2] = f2bf(a[2]); o[3] = f2bf(a[3]);
        o[4] = f2bf(c[0]); o[5] = f2bf(c[1]); o[6] = f2bf(c[2]); o[7] = f2bf(c[3]);
        *(bf16x8*)(xb + (size_t)i * 8) = o;
    } else if (b < 2048 + 768) {
        const int u = b - 2048;
        transpose_tile(qkv_w, qwt, EMB, N3, u % 48, u / 48, t, tid);
    } else {
        const int u = b - 2816;
        transpose_tile(out_w, owt, EMB, EMB, u & 15, u >> 4, t, tid);
    }
}

// ---------------------------------------------------------------------------
// K1: qkv GEMM — 256x192 tile, 256 blocks, 8-phase (R6, passed).
// R7: + XCD-chunked tile swizzle (T1): same-XCD blocks get contiguous tile
// range (2 by-rows) -> A panels L2-local. Bijective (256 % 8 == 0).
// ---------------------------------------------------------------------------
#define MFMA16 __builtin_amdgcn_mfma_f32_16x16x32_bf16

__global__ __launch_bounds__(512, 2)
void mfma_gemm_qkv256(const short* __restrict__ A, const short* __restrict__ BT,
                      const float* __restrict__ bias,
                      short* __restrict__ OQ, short* __restrict__ OK,
                      short* __restrict__ OV)
{
    __shared__ __align__(16) short lds[57344];   // 112 KiB
    const int tid  = threadIdx.x;
    const int lane = tid & 63;
    const int wave = tid >> 6;           // 0..7
    const int wr   = wave >> 2;          // 0..1 (M half)
    const int wc   = wave & 3;           // 0..3 (N quarter, 48 cols each)
    const int frow = lane & 15;
    const int quad = lane >> 4;
    const int q8   = quad * 8;
    // XCD-chunked remap: phys fid -> tile nf so each XCD owns 32 contiguous
    // tiles (2 by-rows x 16 bx) sharing A panels in its L2.
    const int fid = blockIdx.y * 16 + blockIdx.x;
    const int nf  = (fid & 7) * 32 + (fid >> 3);
    const int bx  = nf & 15;             // N tiles: 16 (192 each)
    const int by  = nf >> 4;             // M tiles: 16 (256 each)

    const short* Ab = A  + (size_t)(by * 256) * 1024;
    const short* Bb = BT + (size_t)(bx * 192) * 1024;

    const int trow = tid >> 3;                       // 0..63
    const int ccol = (tid & 7) * 8;                  // dst col chunk, shorts
    const int scol = ccol ^ ((trow & 14) << 2);      // 3-bit swizzled src col
    const int sx   = (frow & 14) << 2;               // read-side XOR, shorts
    const int wcb  = wc * 48 + frow;                 // B fragment row base

#define STG_A(LBASE, GPTR) do {                                             \
        const short* g_ = (GPTR);                                           \
        _Pragma("unroll")                                                   \
        for (int j_ = 0; j_ < 2; ++j_) {                                    \
            const int r_ = j_ * 64 + trow;                                  \
            gload_lds16(g_ + (size_t)r_ * 1024 + scol,                      \
                        &lds[(LBASE) + r_ * 64 + ccol]);                    \
        }                                                                   \
    } while (0)

#define STG_B(LBASE, GPTR) do {                                             \
        const short* g_ = (GPTR);                                           \
        _Pragma("unroll")                                                   \
        for (int j_ = 0; j_ < 3; ++j_) {                                    \
            const int r_ = j_ * 64 + trow;                                  \
            gload_lds16(g_ + (size_t)r_ * 1024 + scol,                      \
                        &lds[(LBASE) + r_ * 64 + ccol]);                    \
        }                                                                   \
    } while (0)

#define LDA(BASE, R, KS) \
    (*(const bf16x8*)&lds[(BASE) + (R) * 64 + ((((KS) * 32) + q8) ^ sx)])

    floatx4 acc[8][3] = {};
    bf16x8  bq[3][2];

#define PHASE(ABASE, BBASE, QD, RDB, VM, ...) do {                          \
        const int Rr_ = wr * 128 + (QD) * 32 + frow;                        \
        bf16x8 a0_ = LDA((ABASE), Rr_,      0);                             \
        bf16x8 a1_ = LDA((ABASE), Rr_,      1);                             \
        bf16x8 a2_ = LDA((ABASE), Rr_ + 16, 0);                             \
        bf16x8 a3_ = LDA((ABASE), Rr_ + 16, 1);                             \
        if (RDB) {                                                          \
            _Pragma("unroll")                                               \
            for (int ni_ = 0; ni_ < 3; ++ni_) {                             \
                bq[ni_][0] = LDA((BBASE), wcb + ni_ * 16, 0);               \
                bq[ni_][1] = LDA((BBASE), wcb + ni_ * 16, 1);               \
            }                                                               \
        }                                                                   \
        __VA_ARGS__;                                                        \
        __builtin_amdgcn_sched_barrier(0);                                  \
        __builtin_amdgcn_s_barrier();                                       \
        asm volatile("s_waitcnt lgkmcnt(0)" ::: "memory");                  \
        __builtin_amdgcn_sched_barrier(0);                                  \
        __builtin_amdgcn_s_setprio(1);                                      \
        _Pragma("unroll")                                                   \
        for (int ni_ = 0; ni_ < 3; ++ni_) {                                 \
            acc[2*(QD)  ][ni_] = MFMA16(a0_, bq[ni_][0], acc[2*(QD)  ][ni_], 0,0,0); \
            acc[2*(QD)  ][ni_] = MFMA16(a1_, bq[ni_][1], acc[2*(QD)  ][ni_], 0,0,0); \
            acc[2*(QD)+1][ni_] = MFMA16(a2_, bq[ni_][0], acc[2*(QD)+1][ni_], 0,0,0); \
            acc[2*(QD)+1][ni_] = MFMA16(a3_, bq[ni_][1], acc[2*(QD)+1][ni_], 0,0,0); \
        }                                                                   \
        __builtin_amdgcn_s_setprio(0);                                      \
        if (VM) asm volatile("s_waitcnt vmcnt(3)" ::: "memory");            \
        __builtin_amdgcn_s_barrier();                                       \
        __builtin_amdgcn_sched_barrier(0);                                  \
    } while (0)

    STG_A(0,     Ab);                    // buf0.A h0
    STG_A(8192,  Ab + 131072);           // buf0.A h1
    STG_B(16384, Bb);                    // buf0.B
    STG_B(45056, Bb + 64);               // buf1.B (tile1)
    asm volatile("s_waitcnt vmcnt(3)" ::: "memory");
    __builtin_amdgcn_s_barrier();
    __builtin_amdgcn_sched_barrier(0);

#pragma unroll 1
    for (int it = 0; it < 8; ++it) {
        const int k1  = (2 * it + 1) * 64;
        const int kn0 = ((2 * it + 2) & 15) * 64;
        const int kn1 = ((2 * it + 3) & 15) * 64;

        PHASE(0, 16384, 0, 1, 0,
              STG_A(28672, Ab + k1); STG_A(36864, Ab + 131072 + k1));
        PHASE(0, 16384, 1, 0, 0, STG_B(16384, Bb + kn0));
        PHASE(0, 16384, 2, 0, 0, ((void)0));
        PHASE(0, 16384, 3, 0, 1, ((void)0));
        PHASE(28672, 45056, 0, 1, 0, STG_A(0, Ab + kn0));
        PHASE(28672, 45056, 1, 0, 0, STG_A(8192, Ab + 131072 + kn0));
        PHASE(28672, 45056, 2, 0, 0, STG_B(45056, Bb + kn1));
        PHASE(28672, 45056, 3, 0, 1, ((void)0));
    }

    __syncthreads();

    const int wbase = wave * 6144;
    const int colg0 = bx * 192 + wc * 48;
    const int L0 = by * 256 + wr * 128;
#pragma unroll
    for (int ni = 0; ni < 3; ++ni) {
        const int n = colg0 + ni * 16 + frow;
        const float bv = bias[n];
        const bool do_elu = (n >> 10) < 2;
#pragma unroll
        for (int mi = 0; mi < 8; ++mi)
#pragma unroll
            for (int r = 0; r < 4; ++r) {
                float v = acc[mi][ni][r] + bv;
                if (do_elu) v = (v > 0.f) ? (v + 1.f) : __expf(v);
                lds[wbase + (mi * 16 + quad * 4 + r) * 48 + ni * 16 + frow] = f2bf(v);
            }
    }
#pragma unroll
    for (int s = 0; s < 12; ++s) {
        const int chunk = s * 64 + lane;     // 768 chunks of 8 shorts
        const int row = chunk / 6, cc = (chunk % 6) * 8;
        const bf16x8 val = *(const bf16x8*)&lds[wbase + row * 48 + cc];
        const int n0 = colg0 + cc;
        const int rsel = n0 >> 10;
        const int h = (n0 & 1023) >> 6;
        const int d = n0 & 63;
        short* base = (rsel == 0) ? OQ : (rsel == 1 ? OK : OV);
        *(bf16x8*)&base[((size_t)(h * L_SEQ + L0 + row)) * HD + d] = val;
    }
#undef PHASE
#undef LDA
#undef STG_A
#undef STG_B
}

// ---------------------------------------------------------------------------
// K5: out-projection GEMM, 64x128 tile (512 blocks = 2/CU).
// R7: full-BK64 rows of 64 shorts + 3-bit XOR swizzle (was 32-short rows ->
// 8-way bank conflict on every fragment ds_read_b128). + XCD-chunked remap.
// LDS: A[64x64]=4096sh @0, B[128x64]=8192sh @4096 (24 KiB).
// ---------------------------------------------------------------------------
__global__ __launch_bounds__(256)
void mfma_gemm_out(const short* __restrict__ A, const short* __restrict__ BT,
                   const float* __restrict__ bias, float* __restrict__ OF,
                   int N, int K)
{
    __shared__ __align__(16) short smem[12288];
    const int tid  = threadIdx.x;
    const int lane = tid & 63;
    const int wave = tid >> 6;
    const int wm = (wave >> 1) * 32;
    const int wn = (wave & 1) * 64;
    // XCD-chunked remap (512 blocks, grid (8,64)): each XCD owns 64 tiles
    // = 8 by-rows x 8 bx, sharing A panels in its L2.
    const int fid = blockIdx.y * 8 + blockIdx.x;
    const int nf  = (fid & 7) * 64 + (fid >> 3);
    const int bx  = nf & 7;
    const int by  = nf >> 3;
    const int frow = lane & 15;
    const int quad = lane >> 4;
    const int q8   = quad << 3;
    const int sx   = (frow & 14) << 2;

    const short* Ab = A  + (size_t)(by * 64) * K;
    const short* Bb = BT + (size_t)(bx * 128) * K;

    floatx4 acc[2][4] = {};

    for (int k0 = 0; k0 < K; k0 += 64) {
        // stage A: 64 rows x 64 cols (2 loads/thread)
#pragma unroll
        for (int q = 0; q < 2; ++q) {
            const int idx = q * 256 + tid;
            const int row = idx >> 3;
            const int c8  = (idx & 7) << 3;
            gload_lds16(Ab + (size_t)row * K + k0 + (c8 ^ ((row & 14) << 2)),
                        &smem[idx << 3]);
        }
        // stage B: 128 rows x 64 cols (4 loads/thread)
#pragma unroll
        for (int q = 0; q < 4; ++q) {
            const int idx = q * 256 + tid;
            const int row = idx >> 3;
            const int c8  = (idx & 7) << 3;
            gload_lds16(Bb + (size_t)row * K + k0 + (c8 ^ ((row & 14) << 2)),
                        &smem[4096 + (idx << 3)]);
        }
        __syncthreads();
        bf16x8 af[2][2], bfv[4][2];
#pragma unroll
        for (int mi = 0; mi < 2; ++mi)
#pragma unroll
            for (int ks = 0; ks < 2; ++ks)
                af[mi][ks] = *(const bf16x8*)
                    &smem[(wm + mi * 16 + frow) * 64 + ((ks * 32 + q8) ^ sx)];
#pragma unroll
        for (int ni = 0; ni < 4; ++ni)
#pragma unroll
            for (int ks = 0; ks < 2; ++ks)
                bfv[ni][ks] = *(const bf16x8*)
                    &smem[4096 + (wn + ni * 16 + frow) * 64 + ((ks * 32 + q8) ^ sx)];
#pragma unroll
        for (int mi = 0; mi < 2; ++mi)
#pragma unroll
            for (int ni = 0; ni < 4; ++ni) {
                acc[mi][ni] = MFMA16(af[mi][0], bfv[ni][0], acc[mi][ni], 0, 0, 0);
                acc[mi][ni] = MFMA16(af[mi][1], bfv[ni][1], acc[mi][ni], 0, 0, 0);
            }
        __syncthreads();
    }

    const int rq = quad << 2;
#pragma unroll
    for (int ni = 0; ni < 4; ++ni) {
        const int n = bx * 128 + wn + ni * 16 + frow;
        const float bv = bias[n];
#pragma unroll
        for (int mi = 0; mi < 2; ++mi)
#pragma unroll
            for (int r = 0; r < 4; ++r) {
                const int m = by * 64 + wm + mi * 16 + rq + r;
                OF[(size_t)m * N + n] = acc[mi][ni][r] + bv;
            }
    }
}

// ---------------------------------------------------------------------------
// K2: per-(head,chunk) state sums, MFMA version. (unchanged, passed)
// ---------------------------------------------------------------------------
#define SP 72

__global__ __launch_bounds__(256, 4)
void chunk_state(const short* __restrict__ Kb, const short* __restrict__ Vb,
                 short* __restrict__ ScTb, float* __restrict__ zc)
{
    __shared__ __align__(16) short Vt[64 * SP];   // V^T: rows e, cols l
    __shared__ __align__(16) short Kt[64 * SP];   // K'^T: rows d, cols l
    const int c = blockIdx.x, h = blockIdx.y;
    const int tid = threadIdx.x, lane = tid & 63, wave = tid >> 6;
    const int frow = lane & 15;
    const int quad = lane >> 4;
    const int fko  = quad << 3;
    const int wm   = wave << 4;
    const short* Kg = Kb + ((size_t)h * L_SEQ + (size_t)c * CHUNK) * HD;
    const short* Vg = Vb + ((size_t)h * L_SEQ + (size_t)c * CHUNK) * HD;

#pragma unroll
    for (int q = 0; q < 2; ++q) {
        const int idx = q * 256 + tid;            // 512 chunks of 8
        const int l = idx >> 3, c8 = (idx & 7) << 3;
        const bf16x8 vv = *(const bf16x8*)&Vg[l * 64 + c8];
        const bf16x8 kk = *(const bf16x8*)&Kg[l * 64 + c8];
#pragma unroll
        for (int j = 0; j < 8; ++j) {
            Vt[(c8 + j) * SP + l] = vv[j];
            Kt[(c8 + j) * SP + l] = kk[j];
        }
    }
    __syncthreads();

    const bf16x8 af0 = *(const bf16x8*)&Vt[(wm + frow) * SP + fko];
    const bf16x8 af1 = *(const bf16x8*)&Vt[(wm + frow) * SP + 32 + fko];

    floatx4 acc[4] = {};
#pragma unroll
    for (int n = 0; n < 4; ++n) {
        const bf16x8 kf0 = *(const bf16x8*)&Kt[(n * 16 + frow) * SP + fko];
        const bf16x8 kf1 = *(const bf16x8*)&Kt[(n * 16 + frow) * SP + 32 + fko];
        acc[n] = MFMA16(af0, kf0, acc[n], 0, 0, 0);
        acc[n] = MFMA16(af1, kf1, acc[n], 0, 0, 0);
    }

    short* Sout = ScTb + (size_t)(h * NCHUNK + c) * 4096;
#pragma unroll
    for (int n = 0; n < 4; ++n)
#pragma unroll
        for (int r = 0; r < 4; ++r) {
            const int e = wm + quad * 4 + r;
            const int d = n * 16 + frow;
            Sout[e * 64 + d] = f2bf(acc[n][r]);
        }

    if (wave == 0) {   // z[d] = sum_l K'[l][d] via all-ones A fragment
        bf16x8 ones;
#pragma unroll
        for (int j = 0; j < 8; ++j) ones[j] = (short)0x3F80;
        floatx4 zacc[4] = {};
#pragma unroll
        for (int n = 0; n < 4; ++n) {
            const bf16x8 kf0 = *(const bf16x8*)&Kt[(n * 16 + frow) * SP + fko];
            const bf16x8 kf1 = *(const bf16x8*)&Kt[(n * 16 + frow) * SP + 32 + fko];
            zacc[n] = MFMA16(ones, kf0, zacc[n], 0, 0, 0);
            zacc[n] = MFMA16(ones, kf1, zacc[n], 0, 0, 0);
        }
        if (quad == 0) {
#pragma unroll
            for (int n = 0; n < 4; ++n)
                zc[(size_t)(h * NCHUNK + c) * 64 + n * 16 + frow] = zacc[n][0];
        }
    }
}

// ---------------------------------------------------------------------------
// K3: exclusive prefix over chunks — R7: 16-deep batches (was 8; halves the
// latency-exposed rounds at 1 block/CU occupancy).
// ---------------------------------------------------------------------------
__global__ __launch_bounds__(256)
void prefix_scan(const short* __restrict__ ScTb, const float* __restrict__ zc,
                 short* __restrict__ S0b)
{
    const int g = blockIdx.x * 256 + threadIdx.x;
    const int h  = g >> 12;
    const int ed = g & 4095;
    const int e  = ed >> 6;
    const int d  = ed & 63;
    const short* src = ScTb + (size_t)h * NCHUNK * 4096 + ed;
    float run = 0.f;
    for (int cb = 0; cb < NCHUNK; cb += 16) {
        short v[16];
#pragma unroll
        for (int u = 0; u < 16; ++u) v[u] = src[(size_t)(cb + u) * 4096];
#pragma unroll
        for (int u = 0; u < 16; ++u) {
            S0b[((size_t)((h * NCHUNK + cb + u) * 65 + e)) * 64 + d] = f2bf(run);
            run += bf2f(v[u]);
        }
    }
    if (g < NH * HD) {
        const int h2 = g >> 6, d2 = g & 63;
        float rz = 0.f;
        for (int cb = 0; cb < NCHUNK; cb += 16) {
            float w[16];
#pragma unroll
            for (int u = 0; u < 16; ++u)
                w[u] = zc[((size_t)(h2 * NCHUNK + cb + u)) * HD + d2];
#pragma unroll
            for (int u = 0; u < 16; ++u) {
                S0b[((size_t)((h2 * NCHUNK + cb + u) * 65 + 64)) * 64 + d2] = f2bf(rz);
                rz += w[u];
            }
        }
    }
}

// ---------------------------------------------------------------------------
// K4: per-(head,chunk) intra-chunk attention — Q,K,V staged in LDS (R5, passed)
// ---------------------------------------------------------------------------
__global__ __launch_bounds__(256)
void chunk_attn(const short* __restrict__ Qb, const short* __restrict__ Kb,
                const short* __restrict__ Vb, const short* __restrict__ S0b,
                short* __restrict__ attn)
{
    __shared__ __align__(16) short Vs[65 * SP];   // V^T, row 64 = ones
    __shared__ __align__(16) short Ks[64 * SP];   // K rows (l x d)
    __shared__ __align__(16) short Qs[64 * SP];   // Q rows (l x d)
    __shared__ __align__(16) short As[64 * SP];
    const int c = blockIdx.x, h = blockIdx.y;
    const int tid = threadIdx.x, lane = tid & 63, wave = tid >> 6;
    const size_t rb = ((size_t)h * L_SEQ + (size_t)c * CHUNK) * HD;
    const short* Qg = Qb + rb;
    const short* Kg = Kb + rb;
    const short* Vg = Vb + rb;
    const short* Sg = S0b + (size_t)(h * NCHUNK + c) * 65 * 64;

#pragma unroll
    for (int q = 0; q < 2; ++q) {
        const int idx = q * 256 + tid;
        const int row = idx >> 3, c8 = (idx & 7) << 3;
        const bf16x8 vv = *(const bf16x8*)&Vg[row * 64 + c8];
        const bf16x8 kk = *(const bf16x8*)&Kg[row * 64 + c8];
        const bf16x8 qq = *(const bf16x8*)&Qg[row * 64 + c8];
#pragma unroll
        for (int j = 0; j < 8; ++j) Vs[(c8 + j) * SP + row] = vv[j];   // V^T
        *(bf16x8*)&Ks[row * SP + c8] = kk;                             // K rows
        *(bf16x8*)&Qs[row * SP + c8] = qq;                             // Q rows
    }
    if (tid < 64) Vs[64 * SP + tid] = (short)0x3F80;                   // ones
    __syncthreads();

    const int frow = lane & 15;
    const int quad = lane >> 4;
    const int fko  = quad << 3;
    const int wm   = wave << 4;

    const bf16x8 qf0 = *(const bf16x8*)&Qs[(wm + frow) * SP + fko];
    const bf16x8 qf1 = *(const bf16x8*)&Qs[(wm + frow) * SP + 32 + fko];

    floatx4 sacc[4] = {};
#pragma unroll
    for (int n = 0; n < 4; ++n) {
        const bf16x8 kf0 = *(const bf16x8*)&Ks[(n * 16 + frow) * SP + fko];
        const bf16x8 kf1 = *(const bf16x8*)&Ks[(n * 16 + frow) * SP + 32 + fko];
        sacc[n] = MFMA16(qf0, kf0, sacc[n], 0, 0, 0);
        sacc[n] = MFMA16(qf1, kf1, sacc[n], 0, 0, 0);
    }
#pragma unroll
    for (int n = 0; n < 4; ++n)
#pragma unroll
        for (int r = 0; r < 4; ++r) {
            const int i = wm + quad * 4 + r;
            const int j = n * 16 + frow;
            As[i * SP + j] = (j <= i) ? f2bf(sacc[n][r]) : (short)0;
        }
    const bf16x8 af0 = *(const bf16x8*)&As[(wm + frow) * SP + fko];
    const bf16x8 af1 = *(const bf16x8*)&As[(wm + frow) * SP + 32 + fko];

    floatx4 oacc[5] = {};
#pragma unroll
    for (int n = 0; n < 4; ++n) {
        const bf16x8 vf0 = *(const bf16x8*)&Vs[(n * 16 + frow) * SP + fko];
        const bf16x8 vf1 = *(const bf16x8*)&Vs[(n * 16 + frow) * SP + 32 + fko];
        oacc[n] = MFMA16(af0, vf0, oacc[n], 0, 0, 0);
        oacc[n] = MFMA16(af1, vf1, oacc[n], 0, 0, 0);
        const bf16x8 sf0 = *(const bf16x8*)&Sg[(n * 16 + frow) * 64 + fko];
        const bf16x8 sf1 = *(const bf16x8*)&Sg[(n * 16 + frow) * 64 + 32 + fko];
        oacc[n] = MFMA16(qf0, sf0, oacc[n], 0, 0, 0);
        oacc[n] = MFMA16(qf1, sf1, oacc[n], 0, 0, 0);
    }
    {   // tile 4: broadcast row 64 (ones / z0) -> col 64 = norm
        const bf16x8 vf0 = *(const bf16x8*)&Vs[64 * SP + fko];
        const bf16x8 vf1 = *(const bf16x8*)&Vs[64 * SP + 32 + fko];
        oacc[4] = MFMA16(af0, vf0, oacc[4], 0, 0, 0);
        oacc[4] = MFMA16(af1, vf1, oacc[4], 0, 0, 0);
        const bf16x8 sf0 = *(const bf16x8*)&Sg[64 * 64 + fko];
        const bf16x8 sf1 = *(const bf16x8*)&Sg[64 * 64 + 32 + fko];
        oacc[4] = MFMA16(qf0, sf0, oacc[4], 0, 0, 0);
        oacc[4] = MFMA16(qf1, sf1, oacc[4], 0, 0, 0);
    }
#pragma unroll
    for (int r = 0; r < 4; ++r) {
        const float norm = __shfl(oacc[4][r], lane & 48) + EPS;
        const float inv = 1.f / norm;
        const int i = wm + quad * 4 + r;
#pragma unroll
        for (int n = 0; n < 4; ++n)
            As[i * SP + n * 16 + frow] = f2bf(oacc[n][r] * inv);
    }
    __syncthreads();
#pragma unroll
    for (int t = 0; t < 2; ++t) {
        const int idx = t * 256 + tid;
        const int row = idx >> 3, c8 = (idx & 7) << 3;
        *(bf16x8*)&attn[(size_t)(c * CHUNK + row) * EMB + h * HD + c8] =
            *(const bf16x8*)&As[row * SP + c8];
    }
}

// ---------------------------------------------------------------------------
extern "C" void kernel_launch(void* const* d_in, const int* in_sizes, int n_in,
                              void* d_out, int out_size, void* d_ws, size_t ws_size,
                              hipStream_t stream)
{
    const float* x     = (const float*)d_in[0];
    const float* qkv_w = (const float*)d_in[1];
    const float* qkv_b = (const float*)d_in[2];
    const float* out_w = (const float*)d_in[3];
    const float* out_b = (const float*)d_in[4];
    float* out = (float*)d_out;

    short* ws    = (short*)d_ws;
    short* Qb    = ws;                   // head-major bf16, 4194304 each
    short* Kb    = Qb + 4194304;
    short* Vb    = Kb + 4194304;
    short* xb    = Vb + 4194304;
    short* qwt   = xb + 4194304;         // 3072 x 1024
    short* owt   = qwt + 3145728;        // 1024 x 1024
    short* attnb = owt + 1048576;        // 4096 x 1024
    short* ScTb  = attnb + 4194304;      // 1024 * 64 * 64
    short* S0b   = ScTb + 4194304;       // 1024 * 65 * 64
    float* zc    = (float*)(S0b + 4259840);    // 65536 fp32

    prep<<<dim3(3072), 256, 0, stream>>>(x, xb, qkv_w, qwt, out_w, owt);
    mfma_gemm_qkv256<<<dim3(N3 / 192, L_SEQ / 256), 512, 0, stream>>>(
        xb, qwt, qkv_b, Qb, Kb, Vb);
    chunk_state<<<dim3(NCHUNK, NH), 256, 0, stream>>>(Kb, Vb, ScTb, zc);
    prefix_scan<<<dim3((NH * 4096) / 256), 256, 0, stream>>>(ScTb, zc, S0b);
    chunk_attn<<<dim3(NCHUNK, NH), 256, 0, stream>>>(Qb, Kb, Vb, S0b, attnb);
    mfma_gemm_out<<<dim3(EMB / 128, L_SEQ / 64), 256, 0, stream>>>(
        attnb, owt, out_b, out, EMB, EMB);
}